// Round 9
// baseline (229.351 us; speedup 1.0000x reference)
//
#include <hip/hip_runtime.h>
#include <hip/hip_fp16.h>
#include <hip/hip_bf16.h>
#include <math.h>

#define L 8192
#define LOG2L 13
#define B 16
#define CIN 64
#define COUT 64
#define KK 64

#define PI_F 3.14159265358979323846f

typedef _Float16 h2 __attribute__((ext_vector_type(2)));

#if defined(__has_builtin)
#if __has_builtin(__builtin_amdgcn_fdot2)
#define FDOT2(a, b, c) __builtin_amdgcn_fdot2((a), (b), (c), false)
#endif
#endif
#ifndef FDOT2
#define FDOT2(a, b, c) ((float)(a).x * (float)(b).x + (float)(a).y * (float)(b).y + (c))
#endif

// XOR swizzle for the bit-reversal scatter phase: bijective involution,
// spreads the 32-way bank collision of bitrev-scatter into <=2-way.
__device__ __forceinline__ int swz(int n) { return n ^ ((n >> 8) & 31); }

// native sincos: v_sin_f32/v_cos_f32 take revolutions, reduce with fract first
__device__ __forceinline__ void nsincos(float ang, float* sn, float* cs) {
    float r = ang * 0.15915494309189535f;   // 1/(2*pi)
    r = r - floorf(r);
    *sn = __builtin_amdgcn_sinf(r);
    *cs = __builtin_amdgcn_cosf(r);
}

// ---------------- kernel 1: partial per-batch min/max of |x| ----------------
__global__ __launch_bounds__(256) void k_reduce1(const float* __restrict__ xr,
                                                 const float* __restrict__ xi,
                                                 float* __restrict__ pmin,
                                                 float* __restrict__ pmax) {
    int bid = blockIdx.x;            // 1024 = 16 batches * 64 slices
    int batch = bid >> 6, slice = bid & 63;
    size_t base = (size_t)batch * CIN * L + (size_t)slice * L;
    int tid = threadIdx.x;
    float mn = 3.4e38f, mx = 0.0f;
    for (int r = 0; r < 32; ++r) {
        int idx = r * 256 + tid;
        float a = xr[base + idx], b = xi[base + idx];
        float m = sqrtf(a * a + b * b);
        mn = fminf(mn, m);
        mx = fmaxf(mx, m);
    }
    __shared__ float smn[4], smx[4];
    for (int off = 32; off >= 1; off >>= 1) {
        mn = fminf(mn, __shfl_down(mn, off));
        mx = fmaxf(mx, __shfl_down(mx, off));
    }
    int wave = tid >> 6;
    if ((tid & 63) == 0) { smn[wave] = mn; smx[wave] = mx; }
    __syncthreads();
    if (tid == 0) {
        for (int w = 1; w < 4; ++w) { mn = fminf(mn, smn[w]); mx = fmaxf(mx, smx[w]); }
        pmin[bid] = mn;
        pmax[bid] = mx;
    }
}

// ---------------- kernel 2: final min/max ----------------
__global__ __launch_bounds__(64) void k_reduce2(const float* __restrict__ pmin,
                                                const float* __restrict__ pmax,
                                                float* __restrict__ mmin,
                                                float* __restrict__ mmax) {
    int b = blockIdx.x, t = threadIdx.x;
    float mn = pmin[b * 64 + t], mx = pmax[b * 64 + t];
    for (int off = 32; off >= 1; off >>= 1) {
        mn = fminf(mn, __shfl_down(mn, off));
        mx = fmaxf(mx, __shfl_down(mx, off));
    }
    if (t == 0) { mmin[b] = mn; mmax[b] = mx; }
}

// ---------------- kernel 3: kernel FFT stats (64-pt DFT, mag+phase) ----------------
__global__ __launch_bounds__(64) void k_kstats(const float* __restrict__ kr,
                                               const float* __restrict__ ki,
                                               float* __restrict__ kmag,
                                               float* __restrict__ kph) {
    int row = blockIdx.x;   // o*64 + j  (4096 rows)
    int k = threadIdx.x;    // output frequency 0..63
    __shared__ float sr[64], si[64];
    sr[k] = kr[row * 64 + k];
    si[k] = ki[row * 64 + k];
    __syncthreads();
    float ar = 0.f, ai = 0.f;
    for (int n = 0; n < 64; ++n) {
        int m = (n * k) & 63;                       // exact mod-64 reduction
        float ang = -2.0f * PI_F * (float)m * (1.0f / 64.0f);
        float s, c;
        __sincosf(ang, &s, &c);
        ar += sr[n] * c - si[n] * s;
        ai += sr[n] * s + si[n] * c;
    }
    kmag[row * 64 + k] = sqrtf(ar * ar + ai * ai);
    kph[row * 64 + k] = atan2f(ai, ar);
}

// ---------------- kernel 4: coupling + forward DIF FFT + bitrev permute ----------------
// x_fft written in NATURAL frequency order as half2 into d_out.
__global__ __launch_bounds__(512) void k_fwd(const float* __restrict__ xr,
                                             const float* __restrict__ xi,
                                             const float* __restrict__ mmin_,
                                             const float* __restrict__ mmax_,
                                             __half2* __restrict__ xfft) {
    __shared__ float sRe[L];
    __shared__ float sIm[L];
    int row = blockIdx.x;          // b*64 + j
    int b = row >> 6;
    int tid = threadIdx.x;
    float mmin = mmin_[b], mmax = mmax_[b];
    float span = mmax - mmin;
    float invden = 1.0f / (span + 1e-10f);
    size_t base = (size_t)row * L;

    for (int rpt = 0; rpt < L / 512; ++rpt) {
        int idx = rpt * 512 + tid;
        float a = xr[base + idx], c = xi[base + idx];
        float m = sqrtf(a * a + c * c);
        float xn = (m - mmin) * invden;
#pragma unroll
        for (int it = 0; it < 5; ++it) xn = 3.8f * xn * (1.0f - xn);
        float mc = xn * span + mmin;
        float scale = (m > 0.0f) ? (mc / m) : 0.0f;
        sRe[idx] = a * scale;
        sIm[idx] = c * scale;
    }

    // stages 0..2 (len 4096,2048,1024): j varies with rpt -> per-butterfly sincos
    for (int s = 0; s < 3; ++s) {
        int lg = LOG2L - 1 - s;
        int len = 1 << lg;
        float fstep = -PI_F / (float)len;
        __syncthreads();
        for (int rpt = 0; rpt < (L / 2) / 512; ++rpt) {
            int t = rpt * 512 + tid;
            int j = t & (len - 1);
            int idx = ((t >> lg) << (lg + 1)) | j;
            float ar = sRe[idx], ai = sIm[idx];
            float br = sRe[idx + len], bi = sIm[idx + len];
            sRe[idx] = ar + br;
            sIm[idx] = ai + bi;
            float dr = ar - br, di = ai - bi;
            float sn, cs;
            nsincos(fstep * (float)j, &sn, &cs);
            sRe[idx + len] = dr * cs - di * sn;
            sIm[idx + len] = dr * sn + di * cs;
        }
    }
    // stages 3..12 (len<=512): j constant per thread -> one sincos per stage
    for (int s = 3; s < LOG2L; ++s) {
        int lg = LOG2L - 1 - s;
        int len = 1 << lg;
        int j = tid & (len - 1);
        float sn, cs;
        nsincos(-PI_F * (float)j / (float)len, &sn, &cs);
        __syncthreads();
#pragma unroll
        for (int rpt = 0; rpt < (L / 2) / 512; ++rpt) {
            int t = rpt * 512 + tid;
            int idx = ((t >> lg) << (lg + 1)) | j;
            float ar = sRe[idx], ai = sIm[idx];
            float br = sRe[idx + len], bi = sIm[idx + len];
            sRe[idx] = ar + br;
            sIm[idx] = ai + bi;
            float dr = ar - br, di = ai - bi;
            sRe[idx + len] = dr * cs - di * sn;
            sIm[idx + len] = dr * sn + di * cs;
        }
    }
    __syncthreads();

    // in-LDS bit-reversal permute (swizzled scatter; bijective, race-free)
    float vr[16], vi[16];
#pragma unroll
    for (int r = 0; r < 16; ++r) {
        int idx = r * 512 + tid;
        vr[r] = sRe[idx]; vi[r] = sIm[idx];
    }
    __syncthreads();
#pragma unroll
    for (int r = 0; r < 16; ++r) {
        int idx = r * 512 + tid;
        int n = (int)(__brev((unsigned)idx) >> 19);   // target natural freq
        int a = swz(n);
        sRe[a] = vr[r]; sIm[a] = vi[r];
    }
    __syncthreads();

#pragma unroll
    for (int r = 0; r < 16; ++r) {
        int n = r * 512 + tid;
        int a = swz(n);
        xfft[base + n] = __floats2half2_rn(sRe[a], sIm[a]);
    }
}

// ---------------- kernel 5: per-frequency complex GEMM (natural order) ----------------
// out_fft[b,i,l] = sum_j x_fft[b,j,l] * kint[i,j,l]
// f16 tiles + v_dot2_f32_f16 MAC:
//   Re(x*k) = dot2((xR,xI),(kR,-kI)), Im(x*k) = dot2((xR,xI),(kI,kR)), f32 accum.
// ktile double-buffered (stage of chunk c+1 overlaps MAC of chunk c across the
// barrier); xtile single-buffered, fed by register prefetch. LDS 40 KB -> 4 blk/CU.
#define PB 32
#define IB 16
#define JC 4
__global__ __launch_bounds__(256) void k_gemm(const h2* __restrict__ xf,
                                              const float* __restrict__ kmag,
                                              const float* __restrict__ kph,
                                              __hip_bfloat162* __restrict__ outfft) {
    __shared__ h2 xtile[JC][B][PB];          // 8 KB
    __shared__ h2 ktile[2][JC][IB][PB][2];   // 32 KB ([0]=(kR,-kI), [1]=(kI,kR))

    int bid = blockIdx.x;
    int ib = bid >> 8;             // 0..3  (siblings of a p-block land on same XCD)
    int pb = bid & 255;
    int p0 = pb * PB;
    int i0 = ib * IB;
    int tid = threadIdx.x;
    int pl = tid & 31;             // p lane
    int gi = (tid >> 5) & 3;       // i-group: 4 i's each
    int gb = tid >> 7;             // b-group: 8 b's each
    int p = p0 + pl;
    int l = p;                     // natural frequency order

    // interpolation parameters (i0k/i1k wave-uniform within the block)
    float pos = ((float)l + 0.5f) * ((float)KK / (float)L) - 0.5f;
    pos = fminf(fmaxf(pos, 0.0f), (float)(KK - 1));
    int i0k = (int)floorf(pos);
    int i1k = min(i0k + 1, KK - 1);
    float w = pos - (float)i0k;

    float accR[8][4], accI[8][4];
#pragma unroll
    for (int bb = 0; bb < 8; ++bb)
#pragma unroll
        for (int q = 0; q < 4; ++q) { accR[bb][q] = 0.f; accI[bb][q] = 0.f; }

    h2 px[8];
    // prefetch chunk 0 and commit immediately
#pragma unroll
    for (int r = 0; r < 8; ++r) {
        int lin = r * 256 + tid;
        int bj = lin >> 5;
        int jj = bj >> 4;
        int bb = bj & 15;
        px[r] = xf[((size_t)(bb * CIN + jj)) * L + p0 + pl];
    }
#pragma unroll
    for (int r = 0; r < 8; ++r) {
        int lin = r * 256 + tid;
        int bj = lin >> 5;
        xtile[bj >> 4][bj & 15][pl] = px[r];
    }
    // stage ktile[0] for chunk 0
#pragma unroll
    for (int r = 0; r < 8; ++r) {
        int lin = r * 256 + tid;
        int ij = lin >> 5;
        int jj = ij >> 4;
        int ii = ij & 15;
        int kb = ((i0 + ii) * CIN + jj) * KK;
        float m0 = kmag[kb + i0k], m1 = kmag[kb + i1k];
        float q0 = kph[kb + i0k],  q1 = kph[kb + i1k];
        float mm = m0 + (m1 - m0) * w;
        float ph = q0 + (q1 - q0) * w;
        float sn, cs;
        nsincos(ph, &sn, &cs);
        float krr = mm * cs, kii = mm * sn;
        h2 ha; ha.x = (_Float16)krr; ha.y = (_Float16)(-kii);
        h2 hb; hb.x = (_Float16)kii; hb.y = (_Float16)krr;
        ktile[0][jj][ii][pl][0] = ha;
        ktile[0][jj][ii][pl][1] = hb;
    }
    // prefetch chunk 1
#pragma unroll
    for (int r = 0; r < 8; ++r) {
        int lin = r * 256 + tid;
        int bj = lin >> 5;
        int jj = bj >> 4;
        int bb = bj & 15;
        px[r] = xf[((size_t)(bb * CIN + JC + jj)) * L + p0 + pl];
    }
    __syncthreads();

    int cur = 0;
    for (int jc = 0; jc < CIN; jc += JC, cur ^= 1) {
        // stage ktile for next chunk into the other buffer (overlaps this MAC)
        if (jc + JC < CIN) {
#pragma unroll
            for (int r = 0; r < 8; ++r) {
                int lin = r * 256 + tid;
                int ij = lin >> 5;
                int jj = ij >> 4;
                int ii = ij & 15;
                int kb = ((i0 + ii) * CIN + jc + JC + jj) * KK;
                float m0 = kmag[kb + i0k], m1 = kmag[kb + i1k];
                float q0 = kph[kb + i0k],  q1 = kph[kb + i1k];
                float mm = m0 + (m1 - m0) * w;
                float ph = q0 + (q1 - q0) * w;
                float sn, cs;
                nsincos(ph, &sn, &cs);
                float krr = mm * cs, kii = mm * sn;
                h2 ha; ha.x = (_Float16)krr; ha.y = (_Float16)(-kii);
                h2 hb; hb.x = (_Float16)kii; hb.y = (_Float16)krr;
                ktile[cur ^ 1][jj][ii][pl][0] = ha;
                ktile[cur ^ 1][jj][ii][pl][1] = hb;
            }
        }

        // MAC on current buffers
#pragma unroll
        for (int jj = 0; jj < JC; ++jj) {
            h2 ka[4], kb2[4];
#pragma unroll
            for (int q = 0; q < 4; ++q) {
                ka[q]  = ktile[cur][jj][gi * 4 + q][pl][0];
                kb2[q] = ktile[cur][jj][gi * 4 + q][pl][1];
            }
#pragma unroll
            for (int bb = 0; bb < 8; ++bb) {
                h2 x = xtile[jj][gb * 8 + bb][pl];
#pragma unroll
                for (int q = 0; q < 4; ++q) {
                    accR[bb][q] = FDOT2(x, ka[q], accR[bb][q]);
                    accI[bb][q] = FDOT2(x, kb2[q], accI[bb][q]);
                }
            }
        }
        __syncthreads();   // MAC done by all; next ktile fully staged

        if (jc + JC < CIN) {
            // commit prefetched x for next chunk, then issue loads for chunk+2
#pragma unroll
            for (int r = 0; r < 8; ++r) {
                int lin = r * 256 + tid;
                int bj = lin >> 5;
                xtile[bj >> 4][bj & 15][pl] = px[r];
            }
            if (jc + 2 * JC < CIN) {
#pragma unroll
                for (int r = 0; r < 8; ++r) {
                    int lin = r * 256 + tid;
                    int bj = lin >> 5;
                    int jj = bj >> 4;
                    int bb = bj & 15;
                    px[r] = xf[((size_t)(bb * CIN + jc + 2 * JC + jj)) * L + p0 + pl];
                }
            }
            __syncthreads();   // xtile ready for next MAC
        }
    }

#pragma unroll
    for (int q = 0; q < 4; ++q) {
        int i = i0 + gi * 4 + q;
#pragma unroll
        for (int bb = 0; bb < 8; ++bb) {
            int bfull = gb * 8 + bb;
            __hip_bfloat162 o;
            o.x = __float2bfloat16(accR[bb][q]);
            o.y = __float2bfloat16(accI[bb][q]);
            outfft[((size_t)(bfull * COUT + i)) * L + p] = o;
        }
    }
}

// ---------------- kernel 6: inverse DIF FFT + bitrev permute + activation ----------------
__global__ __launch_bounds__(512) void k_ifft(const __hip_bfloat162* __restrict__ outfft,
                                              const float* __restrict__ alpha_,
                                              float* __restrict__ out) {
    __shared__ float sRe[L];
    __shared__ float sIm[L];
    int row = blockIdx.x;          // b*64 + i
    int tid = threadIdx.x;
    float alpha = alpha_[0];
    size_t base = (size_t)row * L;

    for (int rpt = 0; rpt < L / 512; ++rpt) {
        int idx = rpt * 512 + tid;
        __hip_bfloat162 v = outfft[base + idx];
        sRe[idx] = __bfloat162float(v.x);
        sIm[idx] = __bfloat162float(v.y);
    }

    // stages 0..2: per-butterfly sincos (positive twiddles)
    for (int s = 0; s < 3; ++s) {
        int lg = LOG2L - 1 - s;
        int len = 1 << lg;
        float fstep = PI_F / (float)len;
        __syncthreads();
        for (int rpt = 0; rpt < (L / 2) / 512; ++rpt) {
            int t = rpt * 512 + tid;
            int j = t & (len - 1);
            int idx = ((t >> lg) << (lg + 1)) | j;
            float ar = sRe[idx], ai = sIm[idx];
            float br = sRe[idx + len], bi = sIm[idx + len];
            sRe[idx] = ar + br;
            sIm[idx] = ai + bi;
            float dr = ar - br, di = ai - bi;
            float sn, cs;
            nsincos(fstep * (float)j, &sn, &cs);
            sRe[idx + len] = dr * cs - di * sn;
            sIm[idx + len] = dr * sn + di * cs;
        }
    }
    // stages 3..12: hoisted sincos
    for (int s = 3; s < LOG2L; ++s) {
        int lg = LOG2L - 1 - s;
        int len = 1 << lg;
        int j = tid & (len - 1);
        float sn, cs;
        nsincos(PI_F * (float)j / (float)len, &sn, &cs);
        __syncthreads();
#pragma unroll
        for (int rpt = 0; rpt < (L / 2) / 512; ++rpt) {
            int t = rpt * 512 + tid;
            int idx = ((t >> lg) << (lg + 1)) | j;
            float ar = sRe[idx], ai = sIm[idx];
            float br = sRe[idx + len], bi = sIm[idx + len];
            sRe[idx] = ar + br;
            sIm[idx] = ai + bi;
            float dr = ar - br, di = ai - bi;
            sRe[idx + len] = dr * cs - di * sn;
            sIm[idx + len] = dr * sn + di * cs;
        }
    }
    __syncthreads();

    // bitrev permute to natural order (swizzled scatter)
    float vr[16], vi[16];
#pragma unroll
    for (int r = 0; r < 16; ++r) {
        int idx = r * 512 + tid;
        vr[r] = sRe[idx]; vi[r] = sIm[idx];
    }
    __syncthreads();
#pragma unroll
    for (int r = 0; r < 16; ++r) {
        int idx = r * 512 + tid;
        int n = (int)(__brev((unsigned)idx) >> 19);
        int a = swz(n);
        sRe[a] = vr[r]; sIm[a] = vi[r];
    }
    __syncthreads();

    const float invN = 1.0f / (float)L;
#pragma unroll
    for (int rpt = 0; rpt < L / 512; ++rpt) {
        int n = rpt * 512 + tid;
        float act = sinf(alpha * (float)n);
        out[base + n] = sRe[swz(n)] * act * invN;   // real part only
    }
}

// ---------------- launch ----------------
extern "C" void kernel_launch(void* const* d_in, const int* in_sizes, int n_in,
                              void* d_out, int out_size, void* d_ws, size_t ws_size,
                              hipStream_t stream) {
    const float* xr = (const float*)d_in[0];
    const float* xi = (const float*)d_in[1];
    const float* kr = (const float*)d_in[2];
    const float* ki = (const float*)d_in[3];
    const float* alpha = (const float*)d_in[4];
    float* out = (float*)d_out;

    // ws layout (total ~35.7 MB):
    //   [0, 33.5MB)  out_fft bf16x2 | kmag 1MB | kph 1MB | reduce scratch
    char* ws = (char*)d_ws;
    size_t OFFT_BYTES = (size_t)B * COUT * L * 4;          // 33,554,432
    __hip_bfloat162* outfft = (__hip_bfloat162*)ws;
    float* kmag = (float*)(ws + OFFT_BYTES);
    float* kph  = (float*)(ws + OFFT_BYTES + (size_t)COUT * CIN * KK * 4);
    float* pmin = (float*)(ws + OFFT_BYTES + (size_t)2 * COUT * CIN * KK * 4);
    float* pmax = pmin + 1024;
    float* mmin = pmax + 1024;
    float* mmax = mmin + 16;

    __half2* xfft = (__half2*)d_out;   // exactly out_size*4 bytes; overwritten by k_ifft

    hipLaunchKernelGGL(k_reduce1, dim3(1024), dim3(256), 0, stream, xr, xi, pmin, pmax);
    hipLaunchKernelGGL(k_reduce2, dim3(16), dim3(64), 0, stream, pmin, pmax, mmin, mmax);
    hipLaunchKernelGGL(k_kstats, dim3(4096), dim3(64), 0, stream, kr, ki, kmag, kph);
    hipLaunchKernelGGL(k_fwd, dim3(1024), dim3(512), 0, stream, xr, xi, mmin, mmax, xfft);
    hipLaunchKernelGGL(k_gemm, dim3(1024), dim3(256), 0, stream, (const h2*)xfft, kmag, kph, outfft);
    hipLaunchKernelGGL(k_ifft, dim3(1024), dim3(512), 0, stream, outfft, alpha, out);
}

// Round 10
// 217.961 us; speedup vs baseline: 1.0523x; 1.0523x over previous
//
#include <hip/hip_runtime.h>
#include <hip/hip_fp16.h>
#include <hip/hip_bf16.h>
#include <math.h>

#define L 8192
#define LOG2L 13
#define B 16
#define CIN 64
#define COUT 64
#define KK 64

#define PI_F 3.14159265358979323846f

typedef float f4v __attribute__((ext_vector_type(4)));
typedef short s8v __attribute__((ext_vector_type(8)));

// XOR swizzle for the bit-reversal scatter phase (FFT kernels)
__device__ __forceinline__ int swz(int n) { return n ^ ((n >> 8) & 31); }

// native sincos (revolutions + fract range reduction)
__device__ __forceinline__ void nsincos(float ang, float* sn, float* cs) {
    float r = ang * 0.15915494309189535f;
    r = r - floorf(r);
    *sn = __builtin_amdgcn_sinf(r);
    *cs = __builtin_amdgcn_cosf(r);
}

// f32 -> bf16 bits, round-to-nearest-even
__device__ __forceinline__ unsigned short f2bf(float f) {
    unsigned u = __builtin_bit_cast(unsigned, f);
    u += 0x7FFFu + ((u >> 16) & 1u);
    return (unsigned short)(u >> 16);
}
// pack two f32 -> bf16x2 dword (round-half-up; cheap, 0.2% worst rel err)
__device__ __forceinline__ unsigned pkbf(float a, float b) {
    unsigned ua = __builtin_bit_cast(unsigned, a) + 0x8000u;
    unsigned ub = __builtin_bit_cast(unsigned, b) + 0x8000u;
    return (ub & 0xFFFF0000u) | (ua >> 16);
}

// ---------------- kernel 1: partial per-batch min/max of |x| ----------------
__global__ __launch_bounds__(256) void k_reduce1(const float* __restrict__ xr,
                                                 const float* __restrict__ xi,
                                                 float* __restrict__ pmin,
                                                 float* __restrict__ pmax) {
    int bid = blockIdx.x;
    int batch = bid >> 6, slice = bid & 63;
    size_t base = (size_t)batch * CIN * L + (size_t)slice * L;
    int tid = threadIdx.x;
    float mn = 3.4e38f, mx = 0.0f;
    for (int r = 0; r < 32; ++r) {
        int idx = r * 256 + tid;
        float a = xr[base + idx], b = xi[base + idx];
        float m = sqrtf(a * a + b * b);
        mn = fminf(mn, m);
        mx = fmaxf(mx, m);
    }
    __shared__ float smn[4], smx[4];
    for (int off = 32; off >= 1; off >>= 1) {
        mn = fminf(mn, __shfl_down(mn, off));
        mx = fmaxf(mx, __shfl_down(mx, off));
    }
    int wave = tid >> 6;
    if ((tid & 63) == 0) { smn[wave] = mn; smx[wave] = mx; }
    __syncthreads();
    if (tid == 0) {
        for (int w = 1; w < 4; ++w) { mn = fminf(mn, smn[w]); mx = fmaxf(mx, smx[w]); }
        pmin[bid] = mn;
        pmax[bid] = mx;
    }
}

// ---------------- kernel 2: final min/max ----------------
__global__ __launch_bounds__(64) void k_reduce2(const float* __restrict__ pmin,
                                                const float* __restrict__ pmax,
                                                float* __restrict__ mmin,
                                                float* __restrict__ mmax) {
    int b = blockIdx.x, t = threadIdx.x;
    float mn = pmin[b * 64 + t], mx = pmax[b * 64 + t];
    for (int off = 32; off >= 1; off >>= 1) {
        mn = fminf(mn, __shfl_down(mn, off));
        mx = fmaxf(mx, __shfl_down(mx, off));
    }
    if (t == 0) { mmin[b] = mn; mmax[b] = mx; }
}

// ---------------- kernel 3: kernel FFT stats, TRANSPOSED tables ----------------
// kmagT[k][i*64+j], kphT[k][i*64+j]; pad row k=64 (copy of k=63) for safe i1k loads.
__global__ __launch_bounds__(64) void k_kstats(const float* __restrict__ kr,
                                               const float* __restrict__ ki,
                                               float* __restrict__ kmagT,
                                               float* __restrict__ kphT) {
    int row = blockIdx.x;   // i*64 + j  (4096 rows)
    int k = threadIdx.x;
    __shared__ float sr[64], si[64];
    sr[k] = kr[row * 64 + k];
    si[k] = ki[row * 64 + k];
    __syncthreads();
    float ar = 0.f, ai = 0.f;
    for (int n = 0; n < 64; ++n) {
        int m = (n * k) & 63;
        float ang = -2.0f * PI_F * (float)m * (1.0f / 64.0f);
        float s, c;
        __sincosf(ang, &s, &c);
        ar += sr[n] * c - si[n] * s;
        ai += sr[n] * s + si[n] * c;
    }
    float mag = sqrtf(ar * ar + ai * ai);
    float ph = atan2f(ai, ar);
    kmagT[(size_t)k * 4096 + row] = mag;
    kphT[(size_t)k * 4096 + row] = ph;
    if (k == 63) {   // pad row 64 (only read when w==0; must be finite)
        kmagT[(size_t)64 * 4096 + row] = mag;
        kphT[(size_t)64 * 4096 + row] = ph;
    }
}

// ---------------- kernel 4: coupling + forward DIF FFT + bitrev permute ----------------
// x_fft written PLANAR bf16 into d_out: R plane [1024][8192], then I plane.
__global__ __launch_bounds__(512) void k_fwd(const float* __restrict__ xr,
                                             const float* __restrict__ xi,
                                             const float* __restrict__ mmin_,
                                             const float* __restrict__ mmax_,
                                             unsigned* __restrict__ xRd) {
    __shared__ float sRe[L];
    __shared__ float sIm[L];
    int row = blockIdx.x;          // b*64 + j
    int b = row >> 6;
    int tid = threadIdx.x;
    float mmin = mmin_[b], mmax = mmax_[b];
    float span = mmax - mmin;
    float invden = 1.0f / (span + 1e-10f);
    size_t base = (size_t)row * L;

    for (int rpt = 0; rpt < L / 512; ++rpt) {
        int idx = rpt * 512 + tid;
        float a = xr[base + idx], c = xi[base + idx];
        float m = sqrtf(a * a + c * c);
        float xn = (m - mmin) * invden;
#pragma unroll
        for (int it = 0; it < 5; ++it) xn = 3.8f * xn * (1.0f - xn);
        float mc = xn * span + mmin;
        float scale = (m > 0.0f) ? (mc / m) : 0.0f;
        sRe[idx] = a * scale;
        sIm[idx] = c * scale;
    }

    // stages 0..2: per-butterfly sincos
    for (int s = 0; s < 3; ++s) {
        int lg = LOG2L - 1 - s;
        int len = 1 << lg;
        float fstep = -PI_F / (float)len;
        __syncthreads();
        for (int rpt = 0; rpt < (L / 2) / 512; ++rpt) {
            int t = rpt * 512 + tid;
            int j = t & (len - 1);
            int idx = ((t >> lg) << (lg + 1)) | j;
            float ar = sRe[idx], ai = sIm[idx];
            float br = sRe[idx + len], bi = sIm[idx + len];
            sRe[idx] = ar + br;
            sIm[idx] = ai + bi;
            float dr = ar - br, di = ai - bi;
            float sn, cs;
            nsincos(fstep * (float)j, &sn, &cs);
            sRe[idx + len] = dr * cs - di * sn;
            sIm[idx + len] = dr * sn + di * cs;
        }
    }
    // stages 3..12: hoisted sincos
    for (int s = 3; s < LOG2L; ++s) {
        int lg = LOG2L - 1 - s;
        int len = 1 << lg;
        int j = tid & (len - 1);
        float sn, cs;
        nsincos(-PI_F * (float)j / (float)len, &sn, &cs);
        __syncthreads();
#pragma unroll
        for (int rpt = 0; rpt < (L / 2) / 512; ++rpt) {
            int t = rpt * 512 + tid;
            int idx = ((t >> lg) << (lg + 1)) | j;
            float ar = sRe[idx], ai = sIm[idx];
            float br = sRe[idx + len], bi = sIm[idx + len];
            sRe[idx] = ar + br;
            sIm[idx] = ai + bi;
            float dr = ar - br, di = ai - bi;
            sRe[idx + len] = dr * cs - di * sn;
            sIm[idx + len] = dr * sn + di * cs;
        }
    }
    __syncthreads();

    // in-LDS bit-reversal permute (swizzled scatter)
    float vr[16], vi[16];
#pragma unroll
    for (int r = 0; r < 16; ++r) {
        int idx = r * 512 + tid;
        vr[r] = sRe[idx]; vi[r] = sIm[idx];
    }
    __syncthreads();
#pragma unroll
    for (int r = 0; r < 16; ++r) {
        int idx = r * 512 + tid;
        int n = (int)(__brev((unsigned)idx) >> 19);
        int a = swz(n);
        sRe[a] = vr[r]; sIm[a] = vi[r];
    }
    __syncthreads();

    // planar bf16 write, natural order (pairs -> dword)
    unsigned* xId = xRd + (size_t)1024 * 4096;
#pragma unroll
    for (int r = 0; r < 8; ++r) {
        int n2 = r * 1024 + tid * 2;
        int a0 = swz(n2), a1 = swz(n2 + 1);
        unsigned vR = ((unsigned)f2bf(sRe[a1]) << 16) | f2bf(sRe[a0]);
        unsigned vI = ((unsigned)f2bf(sIm[a1]) << 16) | f2bf(sIm[a0]);
        size_t o = (size_t)row * 4096 + (n2 >> 1);
        xRd[o] = vR;
        xId[o] = vI;
    }
}

// ---------------- kernel 5: MFMA complex GEMM over frequencies ----------------
// Per p: out[16b x 64i] = x[16b x 64j] * kint[64j x 16i] via mfma_f32_16x16x32_bf16.
// A-frags from LDS (staged planar x); B-frags computed per-lane from transposed
// tables (no LDS). Per-p output transposed through an LDS overlay for coalesced
// stores. Block: 8 p's, 4 waves (2 p each). LDS 37 KB.
#define PB 8
#define REG 4624   // bytes per p-region: 16-aligned, (REG/4)%32==4 (bank spread)
__global__ __launch_bounds__(256) void k_gemm(const unsigned short* __restrict__ xp,
                                              const float* __restrict__ kmagT,
                                              const float* __restrict__ kphT,
                                              unsigned* __restrict__ outd) {
    __shared__ uint4 ldsbuf[(PB * REG) / 16];
    char* lds = (char*)ldsbuf;
    int tid = threadIdx.x;
    int bid = blockIdx.x;
    int pwin = ((bid & 7) << 7) + (bid >> 3);   // XCD-friendly: adjacent windows same XCD
    int p0 = pwin * PB;

    // ---- stage x into LDS: region pp: xR at [b*144+j*2], xI at [2304 + ...] ----
#pragma unroll
    for (int r = 0; r < 8; ++r) {
        int u = r * 256 + tid;         // 0..2047 row-plane units
        int plane = u >> 10;
        int row = u & 1023;
        uint4 v = *(const uint4*)&xp[(size_t)plane * 8388608 + (size_t)row * 8192 + p0];
        int base = plane * 2304 + (row >> 6) * 144 + (row & 63) * 2;
        unsigned short h[8] = {
            (unsigned short)(v.x & 0xFFFF), (unsigned short)(v.x >> 16),
            (unsigned short)(v.y & 0xFFFF), (unsigned short)(v.y >> 16),
            (unsigned short)(v.z & 0xFFFF), (unsigned short)(v.z >> 16),
            (unsigned short)(v.w & 0xFFFF), (unsigned short)(v.w >> 16)};
#pragma unroll
        for (int e = 0; e < 8; ++e)
            *(unsigned short*)&lds[e * REG + base] = h[e];
    }
    __syncthreads();

    int lane = tid & 63;
    int wid = tid >> 6;
    int l15 = lane & 15, l4 = lane >> 4;

    for (int pp = wid * 2; pp < wid * 2 + 2; ++pp) {
        int p = p0 + pp;
        float pos = ((float)p + 0.5f) * ((float)KK / (float)L) - 0.5f;
        pos = fmaxf(pos, 0.0f);
        int i0k = (int)pos;                 // floor (pos>=0)
        float w = pos - (float)i0k;
        if (i0k >= KK - 1) w = 0.0f;        // top clamp: use row i0k only
        const float* mr0 = kmagT + (size_t)i0k * 4096;
        const float* mr1 = mr0 + 4096;
        const float* qr0 = kphT + (size_t)i0k * 4096;
        const float* qr1 = qr0 + 4096;

        f4v accR[4], accI[4];
#pragma unroll
        for (int ic = 0; ic < 4; ++ic) { accR[ic] = (f4v)0.0f; accI[ic] = (f4v)0.0f; }

#pragma unroll
        for (int jc = 0; jc < 2; ++jc) {
            int jb = jc * 32 + l4 * 8;
            s8v xRf = *(const s8v*)&lds[pp * REG + l15 * 144 + jb * 2];
            s8v xIf = *(const s8v*)&lds[pp * REG + 2304 + l15 * 144 + jb * 2];
#pragma unroll
            for (int ic = 0; ic < 4; ++ic) {
                int off = (ic * 16 + l15) * 64 + jb;
                float4 m0a = *(const float4*)(mr0 + off);
                float4 m0b = *(const float4*)(mr0 + off + 4);
                float4 m1a = *(const float4*)(mr1 + off);
                float4 m1b = *(const float4*)(mr1 + off + 4);
                float4 q0a = *(const float4*)(qr0 + off);
                float4 q0b = *(const float4*)(qr0 + off + 4);
                float4 q1a = *(const float4*)(qr1 + off);
                float4 q1b = *(const float4*)(qr1 + off + 4);
                float m0v[8] = {m0a.x, m0a.y, m0a.z, m0a.w, m0b.x, m0b.y, m0b.z, m0b.w};
                float m1v[8] = {m1a.x, m1a.y, m1a.z, m1a.w, m1b.x, m1b.y, m1b.z, m1b.w};
                float q0v[8] = {q0a.x, q0a.y, q0a.z, q0a.w, q0b.x, q0b.y, q0b.z, q0b.w};
                float q1v[8] = {q1a.x, q1a.y, q1a.z, q1a.w, q1b.x, q1b.y, q1b.z, q1b.w};
                float kr[8], ki[8];
#pragma unroll
                for (int e = 0; e < 8; ++e) {
                    float mm = m0v[e] + (m1v[e] - m0v[e]) * w;
                    float ph = q0v[e] + (q1v[e] - q0v[e]) * w;
                    float sn, cs;
                    nsincos(ph, &sn, &cs);
                    kr[e] = mm * cs;
                    ki[e] = mm * sn;
                }
                union { unsigned u[4]; s8v v; } kR, kIp, kIn;
#pragma unroll
                for (int t = 0; t < 4; ++t) {
                    kR.u[t] = pkbf(kr[2 * t], kr[2 * t + 1]);
                    kIp.u[t] = pkbf(ki[2 * t], ki[2 * t + 1]);
                    kIn.u[t] = kIp.u[t] ^ 0x80008000u;
                }
                accR[ic] = __builtin_amdgcn_mfma_f32_16x16x32_bf16(xRf, kR.v, accR[ic], 0, 0, 0);
                accR[ic] = __builtin_amdgcn_mfma_f32_16x16x32_bf16(xIf, kIn.v, accR[ic], 0, 0, 0);
                accI[ic] = __builtin_amdgcn_mfma_f32_16x16x32_bf16(xRf, kIp.v, accI[ic], 0, 0, 0);
                accI[ic] = __builtin_amdgcn_mfma_f32_16x16x32_bf16(xIf, kR.v, accI[ic], 0, 0, 0);
            }
        }

        // overlay: out[b][i] bf16x2 into this p's (now dead) x region
        // C/D layout: col(i)=lane&15, row(b)=(lane>>4)*4+reg  [m89-verified]
#pragma unroll
        for (int ic = 0; ic < 4; ++ic) {
#pragma unroll
            for (int e = 0; e < 4; ++e) {
                int row = (l4 * 4 + e) * 64 + ic * 16 + l15;   // b*64 + i
                unsigned val = ((unsigned)f2bf(accI[ic][e]) << 16) | f2bf(accR[ic][e]);
                *(unsigned*)&lds[pp * REG + row * 4] = val;
            }
        }
    }
    __syncthreads();

    // coalesced store: outd[row*8192 + p0 + pp]
#pragma unroll
    for (int k = 0; k < 32; ++k) {
        int row = k * 32 + (tid >> 3);
        unsigned v = *(const unsigned*)&lds[(tid & 7) * REG + row * 4];
        outd[(size_t)row * 8192 + p0 + (tid & 7)] = v;
    }
}

// ---------------- kernel 6: inverse DIF FFT + bitrev permute + activation ----------------
__global__ __launch_bounds__(512) void k_ifft(const __hip_bfloat162* __restrict__ outfft,
                                              const float* __restrict__ alpha_,
                                              float* __restrict__ out) {
    __shared__ float sRe[L];
    __shared__ float sIm[L];
    int row = blockIdx.x;          // b*64 + i
    int tid = threadIdx.x;
    float alpha = alpha_[0];
    size_t base = (size_t)row * L;

    for (int rpt = 0; rpt < L / 512; ++rpt) {
        int idx = rpt * 512 + tid;
        __hip_bfloat162 v = outfft[base + idx];
        sRe[idx] = __bfloat162float(v.x);
        sIm[idx] = __bfloat162float(v.y);
    }

    for (int s = 0; s < 3; ++s) {
        int lg = LOG2L - 1 - s;
        int len = 1 << lg;
        float fstep = PI_F / (float)len;
        __syncthreads();
        for (int rpt = 0; rpt < (L / 2) / 512; ++rpt) {
            int t = rpt * 512 + tid;
            int j = t & (len - 1);
            int idx = ((t >> lg) << (lg + 1)) | j;
            float ar = sRe[idx], ai = sIm[idx];
            float br = sRe[idx + len], bi = sIm[idx + len];
            sRe[idx] = ar + br;
            sIm[idx] = ai + bi;
            float dr = ar - br, di = ai - bi;
            float sn, cs;
            nsincos(fstep * (float)j, &sn, &cs);
            sRe[idx + len] = dr * cs - di * sn;
            sIm[idx + len] = dr * sn + di * cs;
        }
    }
    for (int s = 3; s < LOG2L; ++s) {
        int lg = LOG2L - 1 - s;
        int len = 1 << lg;
        int j = tid & (len - 1);
        float sn, cs;
        nsincos(PI_F * (float)j / (float)len, &sn, &cs);
        __syncthreads();
#pragma unroll
        for (int rpt = 0; rpt < (L / 2) / 512; ++rpt) {
            int t = rpt * 512 + tid;
            int idx = ((t >> lg) << (lg + 1)) | j;
            float ar = sRe[idx], ai = sIm[idx];
            float br = sRe[idx + len], bi = sIm[idx + len];
            sRe[idx] = ar + br;
            sIm[idx] = ai + bi;
            float dr = ar - br, di = ai - bi;
            sRe[idx + len] = dr * cs - di * sn;
            sIm[idx + len] = dr * sn + di * cs;
        }
    }
    __syncthreads();

    float vr[16], vi[16];
#pragma unroll
    for (int r = 0; r < 16; ++r) {
        int idx = r * 512 + tid;
        vr[r] = sRe[idx]; vi[r] = sIm[idx];
    }
    __syncthreads();
#pragma unroll
    for (int r = 0; r < 16; ++r) {
        int idx = r * 512 + tid;
        int n = (int)(__brev((unsigned)idx) >> 19);
        int a = swz(n);
        sRe[a] = vr[r]; sIm[a] = vi[r];
    }
    __syncthreads();

    const float invN = 1.0f / (float)L;
#pragma unroll
    for (int rpt = 0; rpt < L / 512; ++rpt) {
        int n = rpt * 512 + tid;
        float act = sinf(alpha * (float)n);
        out[base + n] = sRe[swz(n)] * act * invN;
    }
}

// ---------------- launch ----------------
extern "C" void kernel_launch(void* const* d_in, const int* in_sizes, int n_in,
                              void* d_out, int out_size, void* d_ws, size_t ws_size,
                              hipStream_t stream) {
    const float* xr = (const float*)d_in[0];
    const float* xi = (const float*)d_in[1];
    const float* kr = (const float*)d_in[2];
    const float* ki = (const float*)d_in[3];
    const float* alpha = (const float*)d_in[4];
    float* out = (float*)d_out;

    // ws: outfft 33.5MB | kmagT 65*4096*4 | kphT same | reduce scratch  (~35.7MB)
    char* ws = (char*)d_ws;
    size_t OFFT_BYTES = (size_t)B * COUT * L * 4;            // 33,554,432
    size_t TBL_BYTES = (size_t)65 * 4096 * 4;                // 1,064,960
    unsigned* outfft_d = (unsigned*)ws;
    float* kmagT = (float*)(ws + OFFT_BYTES);
    float* kphT  = (float*)(ws + OFFT_BYTES + TBL_BYTES);
    float* pmin  = (float*)(ws + OFFT_BYTES + 2 * TBL_BYTES);
    float* pmax = pmin + 1024;
    float* mmin = pmax + 1024;
    float* mmax = mmin + 16;

    unsigned* xplanar = (unsigned*)d_out;    // planar bf16 x_fft; overwritten by k_ifft

    hipLaunchKernelGGL(k_reduce1, dim3(1024), dim3(256), 0, stream, xr, xi, pmin, pmax);
    hipLaunchKernelGGL(k_reduce2, dim3(16), dim3(64), 0, stream, pmin, pmax, mmin, mmax);
    hipLaunchKernelGGL(k_kstats, dim3(4096), dim3(64), 0, stream, kr, ki, kmagT, kphT);
    hipLaunchKernelGGL(k_fwd, dim3(1024), dim3(512), 0, stream, xr, xi, mmin, mmax, xplanar);
    hipLaunchKernelGGL(k_gemm, dim3(1024), dim3(256), 0, stream,
                       (const unsigned short*)xplanar, kmagT, kphT, outfft_d);
    hipLaunchKernelGGL(k_ifft, dim3(1024), dim3(512), 0, stream,
                       (const __hip_bfloat162*)outfft_d, alpha, out);
}

// Round 11
// 189.109 us; speedup vs baseline: 1.2128x; 1.1526x over previous
//
#include <hip/hip_runtime.h>
#include <hip/hip_fp16.h>
#include <hip/hip_bf16.h>
#include <math.h>

#define L 8192
#define LOG2L 13
#define B 16
#define CIN 64
#define COUT 64
#define KK 64

#define PI_F 3.14159265358979323846f

typedef float f4v __attribute__((ext_vector_type(4)));
typedef short s8v __attribute__((ext_vector_type(8)));

// XOR swizzle for the bit-reversal scatter phase (FFT kernels)
__device__ __forceinline__ int swz(int n) { return n ^ ((n >> 8) & 31); }

// native sincos (revolutions + fract range reduction)
__device__ __forceinline__ void nsincos(float ang, float* sn, float* cs) {
    float r = ang * 0.15915494309189535f;
    r = r - floorf(r);
    *sn = __builtin_amdgcn_sinf(r);
    *cs = __builtin_amdgcn_cosf(r);
}

// f32 -> bf16 bits, round-to-nearest-even
__device__ __forceinline__ unsigned short f2bf(float f) {
    unsigned u = __builtin_bit_cast(unsigned, f);
    u += 0x7FFFu + ((u >> 16) & 1u);
    return (unsigned short)(u >> 16);
}
// pack two f32 -> bf16x2 dword (round-half-up)
__device__ __forceinline__ unsigned pkbf(float a, float b) {
    unsigned ua = __builtin_bit_cast(unsigned, a) + 0x8000u;
    unsigned ub = __builtin_bit_cast(unsigned, b) + 0x8000u;
    return (ub & 0xFFFF0000u) | (ua >> 16);
}

// ---------------- kernel 1: partial per-batch min/max of |x| ----------------
__global__ __launch_bounds__(256) void k_reduce1(const float* __restrict__ xr,
                                                 const float* __restrict__ xi,
                                                 float* __restrict__ pmin,
                                                 float* __restrict__ pmax) {
    int bid = blockIdx.x;
    int batch = bid >> 6, slice = bid & 63;
    size_t base = (size_t)batch * CIN * L + (size_t)slice * L;
    int tid = threadIdx.x;
    float mn = 3.4e38f, mx = 0.0f;
    for (int r = 0; r < 32; ++r) {
        int idx = r * 256 + tid;
        float a = xr[base + idx], b = xi[base + idx];
        float m = sqrtf(a * a + b * b);
        mn = fminf(mn, m);
        mx = fmaxf(mx, m);
    }
    __shared__ float smn[4], smx[4];
    for (int off = 32; off >= 1; off >>= 1) {
        mn = fminf(mn, __shfl_down(mn, off));
        mx = fmaxf(mx, __shfl_down(mx, off));
    }
    int wave = tid >> 6;
    if ((tid & 63) == 0) { smn[wave] = mn; smx[wave] = mx; }
    __syncthreads();
    if (tid == 0) {
        for (int w = 1; w < 4; ++w) { mn = fminf(mn, smn[w]); mx = fmaxf(mx, smx[w]); }
        pmin[bid] = mn;
        pmax[bid] = mx;
    }
}

// ---------------- kernel 2: final min/max ----------------
__global__ __launch_bounds__(64) void k_reduce2(const float* __restrict__ pmin,
                                                const float* __restrict__ pmax,
                                                float* __restrict__ mmin,
                                                float* __restrict__ mmax) {
    int b = blockIdx.x, t = threadIdx.x;
    float mn = pmin[b * 64 + t], mx = pmax[b * 64 + t];
    for (int off = 32; off >= 1; off >>= 1) {
        mn = fminf(mn, __shfl_down(mn, off));
        mx = fmaxf(mx, __shfl_down(mx, off));
    }
    if (t == 0) { mmin[b] = mn; mmax[b] = mx; }
}

// ---------------- kernel 3: kernel FFT stats, TRANSPOSED tables ----------------
__global__ __launch_bounds__(64) void k_kstats(const float* __restrict__ kr,
                                               const float* __restrict__ ki,
                                               float* __restrict__ kmagT,
                                               float* __restrict__ kphT) {
    int row = blockIdx.x;   // i*64 + j  (4096 rows)
    int k = threadIdx.x;
    __shared__ float sr[64], si[64];
    sr[k] = kr[row * 64 + k];
    si[k] = ki[row * 64 + k];
    __syncthreads();
    float ar = 0.f, ai = 0.f;
    for (int n = 0; n < 64; ++n) {
        int m = (n * k) & 63;
        float ang = -2.0f * PI_F * (float)m * (1.0f / 64.0f);
        float s, c;
        __sincosf(ang, &s, &c);
        ar += sr[n] * c - si[n] * s;
        ai += sr[n] * s + si[n] * c;
    }
    float mag = sqrtf(ar * ar + ai * ai);
    float ph = atan2f(ai, ar);
    kmagT[(size_t)k * 4096 + row] = mag;
    kphT[(size_t)k * 4096 + row] = ph;
    if (k == 63) {
        kmagT[(size_t)64 * 4096 + row] = mag;
        kphT[(size_t)64 * 4096 + row] = ph;
    }
}

// ---------------- kernel 4: coupling + radix-4 forward DIF FFT + bitrev permute ----------------
// 6 fused radix-4 passes (stages 0..11) + final radix-2 stage; identical math to
// the radix-2 chain, so output stays bit-reversed-storage and the permute is reused.
__global__ __launch_bounds__(512) void k_fwd(const float* __restrict__ xr,
                                             const float* __restrict__ xi,
                                             const float* __restrict__ mmin_,
                                             const float* __restrict__ mmax_,
                                             unsigned* __restrict__ xRd) {
    __shared__ float sRe[L];
    __shared__ float sIm[L];
    int row = blockIdx.x;          // b*64 + j
    int b = row >> 6;
    int tid = threadIdx.x;
    float mmin = mmin_[b], mmax = mmax_[b];
    float span = mmax - mmin;
    float invden = 1.0f / (span + 1e-10f);
    size_t base = (size_t)row * L;

    for (int rpt = 0; rpt < L / 512; ++rpt) {
        int idx = rpt * 512 + tid;
        float a = xr[base + idx], c = xi[base + idx];
        float m = sqrtf(a * a + c * c);
        float xn = (m - mmin) * invden;
#pragma unroll
        for (int it = 0; it < 5; ++it) xn = 3.8f * xn * (1.0f - xn);
        float mc = xn * span + mmin;
        float scale = (m > 0.0f) ? (mc / m) : 0.0f;
        sRe[idx] = a * scale;
        sIm[idx] = c * scale;
    }

    // radix-4 passes: sp covers stages (2sp, 2sp+1); len1=2*len2, len2=1<<(11-2sp)
    for (int sp = 0; sp < 6; ++sp) {
        int lg2v = 11 - 2 * sp;
        int len2 = 1 << lg2v;
        float hs = 0.f, hc = 1.f;
        if (sp >= 1) {   // len2 <= 512: j1 = tid&(len2-1) constant across rpt
            int j1 = tid & (len2 - 1);
            nsincos(-PI_F * (float)j1 / (float)(2 * len2), &hs, &hc);
        }
        __syncthreads();
#pragma unroll
        for (int rpt = 0; rpt < 4; ++rpt) {
            int t = rpt * 512 + tid;
            int j1 = t & (len2 - 1);
            int idx = ((t >> lg2v) << (lg2v + 2)) | j1;
            float c1 = hc, s1 = hs;
            if (sp == 0) nsincos(-PI_F * (float)j1 / (float)(2 * len2), &s1, &c1);
            float c2 = c1 * c1 - s1 * s1, s2 = 2.f * c1 * s1;
            float u0r = sRe[idx],            u0i = sIm[idx];
            float u1r = sRe[idx + len2],     u1i = sIm[idx + len2];
            float v0r = sRe[idx + 2*len2],   v0i = sIm[idx + 2*len2];
            float v1r = sRe[idx + 3*len2],   v1i = sIm[idx + 3*len2];
            // stage s
            float A0r = u0r + v0r, A0i = u0i + v0i;
            float t0r = u0r - v0r, t0i = u0i - v0i;
            float B0r = t0r * c1 - t0i * s1, B0i = t0r * s1 + t0i * c1;
            float A1r = u1r + v1r, A1i = u1i + v1i;
            float t1r = u1r - v1r, t1i = u1i - v1i;
            float w1r = t1r * c1 - t1i * s1, w1i = t1r * s1 + t1i * c1;
            float B1r = w1i, B1i = -w1r;    // * (-i)  [W(j1+len2,len1) = -i*W]
            // stage s+1 (twiddle W2)
            sRe[idx] = A0r + A1r;            sIm[idx] = A0i + A1i;
            float d0r = A0r - A1r, d0i = A0i - A1i;
            sRe[idx + len2] = d0r * c2 - d0i * s2;
            sIm[idx + len2] = d0r * s2 + d0i * c2;
            sRe[idx + 2*len2] = B0r + B1r;   sIm[idx + 2*len2] = B0i + B1i;
            float d1r = B0r - B1r, d1i = B0i - B1i;
            sRe[idx + 3*len2] = d1r * c2 - d1i * s2;
            sIm[idx + 3*len2] = d1r * s2 + d1i * c2;
        }
    }
    // final radix-2 stage (len=1, twiddle 1)
    __syncthreads();
#pragma unroll
    for (int rpt = 0; rpt < 8; ++rpt) {
        int idx = (rpt * 512 + tid) * 2;
        float ar = sRe[idx], ai = sIm[idx];
        float br = sRe[idx + 1], bi = sIm[idx + 1];
        sRe[idx] = ar + br;     sIm[idx] = ai + bi;
        sRe[idx + 1] = ar - br; sIm[idx + 1] = ai - bi;
    }
    __syncthreads();

    // in-LDS bit-reversal permute (swizzled scatter)
    float vr[16], vi[16];
#pragma unroll
    for (int r = 0; r < 16; ++r) {
        int idx = r * 512 + tid;
        vr[r] = sRe[idx]; vi[r] = sIm[idx];
    }
    __syncthreads();
#pragma unroll
    for (int r = 0; r < 16; ++r) {
        int idx = r * 512 + tid;
        int n = (int)(__brev((unsigned)idx) >> 19);
        int a = swz(n);
        sRe[a] = vr[r]; sIm[a] = vi[r];
    }
    __syncthreads();

    // planar bf16 write, natural order
    unsigned* xId = xRd + (size_t)1024 * 4096;
#pragma unroll
    for (int r = 0; r < 8; ++r) {
        int n2 = r * 1024 + tid * 2;
        int a0 = swz(n2), a1 = swz(n2 + 1);
        unsigned vR = ((unsigned)f2bf(sRe[a1]) << 16) | f2bf(sRe[a0]);
        unsigned vI = ((unsigned)f2bf(sIm[a1]) << 16) | f2bf(sIm[a0]);
        size_t o = (size_t)row * 4096 + (n2 >> 1);
        xRd[o] = vR;
        xId[o] = vI;
    }
}

// ---------------- kernel 5: MFMA complex GEMM over frequencies ----------------
#define PB 8
#define REG 4624
__global__ __launch_bounds__(256) void k_gemm(const unsigned short* __restrict__ xp,
                                              const float* __restrict__ kmagT,
                                              const float* __restrict__ kphT,
                                              unsigned* __restrict__ outd) {
    __shared__ uint4 ldsbuf[(PB * REG) / 16];
    char* lds = (char*)ldsbuf;
    int tid = threadIdx.x;
    int bid = blockIdx.x;
    int pwin = ((bid & 7) << 7) + (bid >> 3);
    int p0 = pwin * PB;

#pragma unroll
    for (int r = 0; r < 8; ++r) {
        int u = r * 256 + tid;
        int plane = u >> 10;
        int row = u & 1023;
        uint4 v = *(const uint4*)&xp[(size_t)plane * 8388608 + (size_t)row * 8192 + p0];
        int base = plane * 2304 + (row >> 6) * 144 + (row & 63) * 2;
        unsigned short h[8] = {
            (unsigned short)(v.x & 0xFFFF), (unsigned short)(v.x >> 16),
            (unsigned short)(v.y & 0xFFFF), (unsigned short)(v.y >> 16),
            (unsigned short)(v.z & 0xFFFF), (unsigned short)(v.z >> 16),
            (unsigned short)(v.w & 0xFFFF), (unsigned short)(v.w >> 16)};
#pragma unroll
        for (int e = 0; e < 8; ++e)
            *(unsigned short*)&lds[e * REG + base] = h[e];
    }
    __syncthreads();

    int lane = tid & 63;
    int wid = tid >> 6;
    int l15 = lane & 15, l4 = lane >> 4;

    for (int pp = wid * 2; pp < wid * 2 + 2; ++pp) {
        int p = p0 + pp;
        float pos = ((float)p + 0.5f) * ((float)KK / (float)L) - 0.5f;
        pos = fmaxf(pos, 0.0f);
        int i0k = (int)pos;
        float w = pos - (float)i0k;
        if (i0k >= KK - 1) w = 0.0f;
        const float* mr0 = kmagT + (size_t)i0k * 4096;
        const float* mr1 = mr0 + 4096;
        const float* qr0 = kphT + (size_t)i0k * 4096;
        const float* qr1 = qr0 + 4096;

        f4v accR[4], accI[4];
#pragma unroll
        for (int ic = 0; ic < 4; ++ic) { accR[ic] = (f4v)0.0f; accI[ic] = (f4v)0.0f; }

#pragma unroll
        for (int jc = 0; jc < 2; ++jc) {
            int jb = jc * 32 + l4 * 8;
            s8v xRf = *(const s8v*)&lds[pp * REG + l15 * 144 + jb * 2];
            s8v xIf = *(const s8v*)&lds[pp * REG + 2304 + l15 * 144 + jb * 2];
#pragma unroll
            for (int ic = 0; ic < 4; ++ic) {
                int off = (ic * 16 + l15) * 64 + jb;
                float4 m0a = *(const float4*)(mr0 + off);
                float4 m0b = *(const float4*)(mr0 + off + 4);
                float4 m1a = *(const float4*)(mr1 + off);
                float4 m1b = *(const float4*)(mr1 + off + 4);
                float4 q0a = *(const float4*)(qr0 + off);
                float4 q0b = *(const float4*)(qr0 + off + 4);
                float4 q1a = *(const float4*)(qr1 + off);
                float4 q1b = *(const float4*)(qr1 + off + 4);
                float m0v[8] = {m0a.x, m0a.y, m0a.z, m0a.w, m0b.x, m0b.y, m0b.z, m0b.w};
                float m1v[8] = {m1a.x, m1a.y, m1a.z, m1a.w, m1b.x, m1b.y, m1b.z, m1b.w};
                float q0v[8] = {q0a.x, q0a.y, q0a.z, q0a.w, q0b.x, q0b.y, q0b.z, q0b.w};
                float q1v[8] = {q1a.x, q1a.y, q1a.z, q1a.w, q1b.x, q1b.y, q1b.z, q1b.w};
                float kr[8], ki[8];
#pragma unroll
                for (int e = 0; e < 8; ++e) {
                    float mm = m0v[e] + (m1v[e] - m0v[e]) * w;
                    float ph = q0v[e] + (q1v[e] - q0v[e]) * w;
                    float sn, cs;
                    nsincos(ph, &sn, &cs);
                    kr[e] = mm * cs;
                    ki[e] = mm * sn;
                }
                union { unsigned u[4]; s8v v; } kR, kIp, kIn;
#pragma unroll
                for (int t = 0; t < 4; ++t) {
                    kR.u[t] = pkbf(kr[2 * t], kr[2 * t + 1]);
                    kIp.u[t] = pkbf(ki[2 * t], ki[2 * t + 1]);
                    kIn.u[t] = kIp.u[t] ^ 0x80008000u;
                }
                accR[ic] = __builtin_amdgcn_mfma_f32_16x16x32_bf16(xRf, kR.v, accR[ic], 0, 0, 0);
                accR[ic] = __builtin_amdgcn_mfma_f32_16x16x32_bf16(xIf, kIn.v, accR[ic], 0, 0, 0);
                accI[ic] = __builtin_amdgcn_mfma_f32_16x16x32_bf16(xRf, kIp.v, accI[ic], 0, 0, 0);
                accI[ic] = __builtin_amdgcn_mfma_f32_16x16x32_bf16(xIf, kR.v, accI[ic], 0, 0, 0);
            }
        }

#pragma unroll
        for (int ic = 0; ic < 4; ++ic) {
#pragma unroll
            for (int e = 0; e < 4; ++e) {
                int row = (l4 * 4 + e) * 64 + ic * 16 + l15;
                unsigned val = ((unsigned)f2bf(accI[ic][e]) << 16) | f2bf(accR[ic][e]);
                *(unsigned*)&lds[pp * REG + row * 4] = val;
            }
        }
    }
    __syncthreads();

#pragma unroll
    for (int k = 0; k < 32; ++k) {
        int row = k * 32 + (tid >> 3);
        unsigned v = *(const unsigned*)&lds[(tid & 7) * REG + row * 4];
        outd[(size_t)row * 8192 + p0 + (tid & 7)] = v;
    }
}

// ---------------- kernel 6: radix-4 inverse DIF FFT + bitrev permute + activation ----------------
__global__ __launch_bounds__(512) void k_ifft(const __hip_bfloat162* __restrict__ outfft,
                                              const float* __restrict__ alpha_,
                                              float* __restrict__ out) {
    __shared__ float sRe[L];
    __shared__ float sIm[L];
    int row = blockIdx.x;          // b*64 + i
    int tid = threadIdx.x;
    float alpha = alpha_[0];
    size_t base = (size_t)row * L;

    for (int rpt = 0; rpt < L / 512; ++rpt) {
        int idx = rpt * 512 + tid;
        __hip_bfloat162 v = outfft[base + idx];
        sRe[idx] = __bfloat162float(v.x);
        sIm[idx] = __bfloat162float(v.y);
    }

    // radix-4 passes, POSITIVE twiddles; W(j1+len2,len1) = +i*W
    for (int sp = 0; sp < 6; ++sp) {
        int lg2v = 11 - 2 * sp;
        int len2 = 1 << lg2v;
        float hs = 0.f, hc = 1.f;
        if (sp >= 1) {
            int j1 = tid & (len2 - 1);
            nsincos(PI_F * (float)j1 / (float)(2 * len2), &hs, &hc);
        }
        __syncthreads();
#pragma unroll
        for (int rpt = 0; rpt < 4; ++rpt) {
            int t = rpt * 512 + tid;
            int j1 = t & (len2 - 1);
            int idx = ((t >> lg2v) << (lg2v + 2)) | j1;
            float c1 = hc, s1 = hs;
            if (sp == 0) nsincos(PI_F * (float)j1 / (float)(2 * len2), &s1, &c1);
            float c2 = c1 * c1 - s1 * s1, s2 = 2.f * c1 * s1;
            float u0r = sRe[idx],            u0i = sIm[idx];
            float u1r = sRe[idx + len2],     u1i = sIm[idx + len2];
            float v0r = sRe[idx + 2*len2],   v0i = sIm[idx + 2*len2];
            float v1r = sRe[idx + 3*len2],   v1i = sIm[idx + 3*len2];
            float A0r = u0r + v0r, A0i = u0i + v0i;
            float t0r = u0r - v0r, t0i = u0i - v0i;
            float B0r = t0r * c1 - t0i * s1, B0i = t0r * s1 + t0i * c1;
            float A1r = u1r + v1r, A1i = u1i + v1i;
            float t1r = u1r - v1r, t1i = u1i - v1i;
            float w1r = t1r * c1 - t1i * s1, w1i = t1r * s1 + t1i * c1;
            float B1r = -w1i, B1i = w1r;    // * (+i)
            sRe[idx] = A0r + A1r;            sIm[idx] = A0i + A1i;
            float d0r = A0r - A1r, d0i = A0i - A1i;
            sRe[idx + len2] = d0r * c2 - d0i * s2;
            sIm[idx + len2] = d0r * s2 + d0i * c2;
            sRe[idx + 2*len2] = B0r + B1r;   sIm[idx + 2*len2] = B0i + B1i;
            float d1r = B0r - B1r, d1i = B0i - B1i;
            sRe[idx + 3*len2] = d1r * c2 - d1i * s2;
            sIm[idx + 3*len2] = d1r * s2 + d1i * c2;
        }
    }
    __syncthreads();
#pragma unroll
    for (int rpt = 0; rpt < 8; ++rpt) {
        int idx = (rpt * 512 + tid) * 2;
        float ar = sRe[idx], ai = sIm[idx];
        float br = sRe[idx + 1], bi = sIm[idx + 1];
        sRe[idx] = ar + br;     sIm[idx] = ai + bi;
        sRe[idx + 1] = ar - br; sIm[idx + 1] = ai - bi;
    }
    __syncthreads();

    float vr[16], vi[16];
#pragma unroll
    for (int r = 0; r < 16; ++r) {
        int idx = r * 512 + tid;
        vr[r] = sRe[idx]; vi[r] = sIm[idx];
    }
    __syncthreads();
#pragma unroll
    for (int r = 0; r < 16; ++r) {
        int idx = r * 512 + tid;
        int n = (int)(__brev((unsigned)idx) >> 19);
        int a = swz(n);
        sRe[a] = vr[r]; sIm[a] = vi[r];
    }
    __syncthreads();

    const float invN = 1.0f / (float)L;
#pragma unroll
    for (int rpt = 0; rpt < L / 512; ++rpt) {
        int n = rpt * 512 + tid;
        float act = sinf(alpha * (float)n);
        out[base + n] = sRe[swz(n)] * act * invN;
    }
}

// ---------------- launch ----------------
extern "C" void kernel_launch(void* const* d_in, const int* in_sizes, int n_in,
                              void* d_out, int out_size, void* d_ws, size_t ws_size,
                              hipStream_t stream) {
    const float* xr = (const float*)d_in[0];
    const float* xi = (const float*)d_in[1];
    const float* kr = (const float*)d_in[2];
    const float* ki = (const float*)d_in[3];
    const float* alpha = (const float*)d_in[4];
    float* out = (float*)d_out;

    char* ws = (char*)d_ws;
    size_t OFFT_BYTES = (size_t)B * COUT * L * 4;
    size_t TBL_BYTES = (size_t)65 * 4096 * 4;
    unsigned* outfft_d = (unsigned*)ws;
    float* kmagT = (float*)(ws + OFFT_BYTES);
    float* kphT  = (float*)(ws + OFFT_BYTES + TBL_BYTES);
    float* pmin  = (float*)(ws + OFFT_BYTES + 2 * TBL_BYTES);
    float* pmax = pmin + 1024;
    float* mmin = pmax + 1024;
    float* mmax = mmin + 16;

    unsigned* xplanar = (unsigned*)d_out;

    hipLaunchKernelGGL(k_reduce1, dim3(1024), dim3(256), 0, stream, xr, xi, pmin, pmax);
    hipLaunchKernelGGL(k_reduce2, dim3(16), dim3(64), 0, stream, pmin, pmax, mmin, mmax);
    hipLaunchKernelGGL(k_kstats, dim3(4096), dim3(64), 0, stream, kr, ki, kmagT, kphT);
    hipLaunchKernelGGL(k_fwd, dim3(1024), dim3(512), 0, stream, xr, xi, mmin, mmax, xplanar);
    hipLaunchKernelGGL(k_gemm, dim3(1024), dim3(256), 0, stream,
                       (const unsigned short*)xplanar, kmagT, kphT, outfft_d);
    hipLaunchKernelGGL(k_ifft, dim3(1024), dim3(512), 0, stream,
                       (const __hip_bfloat162*)outfft_d, alpha, out);
}

// Round 12
// 159.664 us; speedup vs baseline: 1.4365x; 1.1844x over previous
//
#include <hip/hip_runtime.h>
#include <hip/hip_fp16.h>
#include <hip/hip_bf16.h>
#include <math.h>

#define L 8192
#define LOG2L 13
#define B 16
#define CIN 64
#define COUT 64
#define KK 64

#define PI_F 3.14159265358979323846f

typedef float f4v __attribute__((ext_vector_type(4)));
typedef short s8v __attribute__((ext_vector_type(8)));

// XOR swizzle for the bit-reversal scatter phase (FFT kernels)
__device__ __forceinline__ int swz(int n) { return n ^ ((n >> 8) & 31); }

// native sincos (revolutions + fract range reduction)
__device__ __forceinline__ void nsincos(float ang, float* sn, float* cs) {
    float r = ang * 0.15915494309189535f;
    r = r - floorf(r);
    *sn = __builtin_amdgcn_sinf(r);
    *cs = __builtin_amdgcn_cosf(r);
}

// f32 -> bf16 bits, round-to-nearest-even
__device__ __forceinline__ unsigned short f2bf(float f) {
    unsigned u = __builtin_bit_cast(unsigned, f);
    u += 0x7FFFu + ((u >> 16) & 1u);
    return (unsigned short)(u >> 16);
}
// pack two f32 -> bf16x2 dword (round-half-up)
__device__ __forceinline__ unsigned pkbf(float a, float b) {
    unsigned ua = __builtin_bit_cast(unsigned, a) + 0x8000u;
    unsigned ub = __builtin_bit_cast(unsigned, b) + 0x8000u;
    return (ub & 0xFFFF0000u) | (ua >> 16);
}

// ---------------- kernel 1: partial per-batch min/max of |x| ----------------
__global__ __launch_bounds__(256) void k_reduce1(const float* __restrict__ xr,
                                                 const float* __restrict__ xi,
                                                 float* __restrict__ pmin,
                                                 float* __restrict__ pmax) {
    int bid = blockIdx.x;
    int batch = bid >> 6, slice = bid & 63;
    size_t base = (size_t)batch * CIN * L + (size_t)slice * L;
    int tid = threadIdx.x;
    float mn = 3.4e38f, mx = 0.0f;
    for (int r = 0; r < 32; ++r) {
        int idx = r * 256 + tid;
        float a = xr[base + idx], b = xi[base + idx];
        float m = sqrtf(a * a + b * b);
        mn = fminf(mn, m);
        mx = fmaxf(mx, m);
    }
    __shared__ float smn[4], smx[4];
    for (int off = 32; off >= 1; off >>= 1) {
        mn = fminf(mn, __shfl_down(mn, off));
        mx = fmaxf(mx, __shfl_down(mx, off));
    }
    int wave = tid >> 6;
    if ((tid & 63) == 0) { smn[wave] = mn; smx[wave] = mx; }
    __syncthreads();
    if (tid == 0) {
        for (int w = 1; w < 4; ++w) { mn = fminf(mn, smn[w]); mx = fmaxf(mx, smx[w]); }
        pmin[bid] = mn;
        pmax[bid] = mx;
    }
}

// ---------------- kernel 2: final min/max ----------------
__global__ __launch_bounds__(64) void k_reduce2(const float* __restrict__ pmin,
                                                const float* __restrict__ pmax,
                                                float* __restrict__ mmin,
                                                float* __restrict__ mmax) {
    int b = blockIdx.x, t = threadIdx.x;
    float mn = pmin[b * 64 + t], mx = pmax[b * 64 + t];
    for (int off = 32; off >= 1; off >>= 1) {
        mn = fminf(mn, __shfl_down(mn, off));
        mx = fmaxf(mx, __shfl_down(mx, off));
    }
    if (t == 0) { mmin[b] = mn; mmax[b] = mx; }
}

// ---------------- kernel 3: kernel FFT stats, B-FRAGMENT-PACKED tables ----------------
// P[k*4096 + (ic*2+jc)*512 + lane*8 + e] where i=ic*16+(lane&15), j=jc*32+(lane>>4)*8+e.
// A wave's (ic,jc) table read is then 64 lanes x 32B contiguous. Pad row k=64.
__global__ __launch_bounds__(64) void k_kstats(const float* __restrict__ kr,
                                               const float* __restrict__ ki,
                                               float* __restrict__ Pmag,
                                               float* __restrict__ Pph) {
    int row = blockIdx.x;   // io*64 + jn  (4096 rows)
    int k = threadIdx.x;
    __shared__ float sr[64], si[64];
    sr[k] = kr[row * 64 + k];
    si[k] = ki[row * 64 + k];
    __syncthreads();
    float ar = 0.f, ai = 0.f;
    for (int n = 0; n < 64; ++n) {
        int m = (n * k) & 63;
        float ang = -2.0f * PI_F * (float)m * (1.0f / 64.0f);
        float s, c;
        __sincosf(ang, &s, &c);
        ar += sr[n] * c - si[n] * s;
        ai += sr[n] * s + si[n] * c;
    }
    float mag = sqrtf(ar * ar + ai * ai);
    float ph = atan2f(ai, ar);
    int io = row >> 6, jn = row & 63;
    int ic = io >> 4, l15 = io & 15;
    int jc = jn >> 5, hi = (jn >> 3) & 3, e = jn & 7;
    int lane = hi * 16 + l15;
    size_t off = (size_t)k * 4096 + (ic * 2 + jc) * 512 + lane * 8 + e;
    Pmag[off] = mag;
    Pph[off] = ph;
    if (k == 63) {           // pad row 64 (read when i0k==63, w==0; must be finite)
        Pmag[off + 4096] = mag;
        Pph[off + 4096] = ph;
    }
}

// ---------------- kernel 4: coupling + radix-4 forward DIF FFT + bitrev permute ----------------
__global__ __launch_bounds__(512) void k_fwd(const float* __restrict__ xr,
                                             const float* __restrict__ xi,
                                             const float* __restrict__ mmin_,
                                             const float* __restrict__ mmax_,
                                             unsigned* __restrict__ xRd) {
    __shared__ float sRe[L];
    __shared__ float sIm[L];
    int row = blockIdx.x;          // b*64 + j
    int b = row >> 6;
    int tid = threadIdx.x;
    float mmin = mmin_[b], mmax = mmax_[b];
    float span = mmax - mmin;
    float invden = 1.0f / (span + 1e-10f);
    size_t base = (size_t)row * L;

    for (int rpt = 0; rpt < L / 512; ++rpt) {
        int idx = rpt * 512 + tid;
        float a = xr[base + idx], c = xi[base + idx];
        float m = sqrtf(a * a + c * c);
        float xn = (m - mmin) * invden;
#pragma unroll
        for (int it = 0; it < 5; ++it) xn = 3.8f * xn * (1.0f - xn);
        float mc = xn * span + mmin;
        float scale = (m > 0.0f) ? (mc / m) : 0.0f;
        sRe[idx] = a * scale;
        sIm[idx] = c * scale;
    }

    for (int sp = 0; sp < 6; ++sp) {
        int lg2v = 11 - 2 * sp;
        int len2 = 1 << lg2v;
        float hs = 0.f, hc = 1.f;
        if (sp >= 1) {
            int j1 = tid & (len2 - 1);
            nsincos(-PI_F * (float)j1 / (float)(2 * len2), &hs, &hc);
        }
        __syncthreads();
#pragma unroll
        for (int rpt = 0; rpt < 4; ++rpt) {
            int t = rpt * 512 + tid;
            int j1 = t & (len2 - 1);
            int idx = ((t >> lg2v) << (lg2v + 2)) | j1;
            float c1 = hc, s1 = hs;
            if (sp == 0) nsincos(-PI_F * (float)j1 / (float)(2 * len2), &s1, &c1);
            float c2 = c1 * c1 - s1 * s1, s2 = 2.f * c1 * s1;
            float u0r = sRe[idx],            u0i = sIm[idx];
            float u1r = sRe[idx + len2],     u1i = sIm[idx + len2];
            float v0r = sRe[idx + 2*len2],   v0i = sIm[idx + 2*len2];
            float v1r = sRe[idx + 3*len2],   v1i = sIm[idx + 3*len2];
            float A0r = u0r + v0r, A0i = u0i + v0i;
            float t0r = u0r - v0r, t0i = u0i - v0i;
            float B0r = t0r * c1 - t0i * s1, B0i = t0r * s1 + t0i * c1;
            float A1r = u1r + v1r, A1i = u1i + v1i;
            float t1r = u1r - v1r, t1i = u1i - v1i;
            float w1r = t1r * c1 - t1i * s1, w1i = t1r * s1 + t1i * c1;
            float B1r = w1i, B1i = -w1r;    // * (-i)
            sRe[idx] = A0r + A1r;            sIm[idx] = A0i + A1i;
            float d0r = A0r - A1r, d0i = A0i - A1i;
            sRe[idx + len2] = d0r * c2 - d0i * s2;
            sIm[idx + len2] = d0r * s2 + d0i * c2;
            sRe[idx + 2*len2] = B0r + B1r;   sIm[idx + 2*len2] = B0i + B1i;
            float d1r = B0r - B1r, d1i = B0i - B1i;
            sRe[idx + 3*len2] = d1r * c2 - d1i * s2;
            sIm[idx + 3*len2] = d1r * s2 + d1i * c2;
        }
    }
    __syncthreads();
#pragma unroll
    for (int rpt = 0; rpt < 8; ++rpt) {
        int idx = (rpt * 512 + tid) * 2;
        float ar = sRe[idx], ai = sIm[idx];
        float br = sRe[idx + 1], bi = sIm[idx + 1];
        sRe[idx] = ar + br;     sIm[idx] = ai + bi;
        sRe[idx + 1] = ar - br; sIm[idx + 1] = ai - bi;
    }
    __syncthreads();

    float vr[16], vi[16];
#pragma unroll
    for (int r = 0; r < 16; ++r) {
        int idx = r * 512 + tid;
        vr[r] = sRe[idx]; vi[r] = sIm[idx];
    }
    __syncthreads();
#pragma unroll
    for (int r = 0; r < 16; ++r) {
        int idx = r * 512 + tid;
        int n = (int)(__brev((unsigned)idx) >> 19);
        int a = swz(n);
        sRe[a] = vr[r]; sIm[a] = vi[r];
    }
    __syncthreads();

    unsigned* xId = xRd + (size_t)1024 * 4096;
#pragma unroll
    for (int r = 0; r < 8; ++r) {
        int n2 = r * 1024 + tid * 2;
        int a0 = swz(n2), a1 = swz(n2 + 1);
        unsigned vR = ((unsigned)f2bf(sRe[a1]) << 16) | f2bf(sRe[a0]);
        unsigned vI = ((unsigned)f2bf(sIm[a1]) << 16) | f2bf(sIm[a0]);
        size_t o = (size_t)row * 4096 + (n2 >> 1);
        xRd[o] = vR;
        xId[o] = vI;
    }
}

// ---------------- kernel 5: MFMA complex GEMM over frequencies ----------------
// Packed-table loads are fully coalesced; loads hoisted over the wave's p-pair
// (both p's provably share i0k). Block: 8 p's, 4 waves (2 p each). LDS 37 KB.
#define PB 8
#define REG 4624
__global__ __launch_bounds__(256) void k_gemm(const unsigned short* __restrict__ xp,
                                              const float* __restrict__ Pmag,
                                              const float* __restrict__ Pph,
                                              unsigned* __restrict__ outd) {
    __shared__ uint4 ldsbuf[(PB * REG) / 16];
    char* lds = (char*)ldsbuf;
    int tid = threadIdx.x;
    int bid = blockIdx.x;
    int pwin = ((bid & 7) << 7) + (bid >> 3);
    int p0 = pwin * PB;

#pragma unroll
    for (int r = 0; r < 8; ++r) {
        int u = r * 256 + tid;
        int plane = u >> 10;
        int row = u & 1023;
        uint4 v = *(const uint4*)&xp[(size_t)plane * 8388608 + (size_t)row * 8192 + p0];
        int base = plane * 2304 + (row >> 6) * 144 + (row & 63) * 2;
        unsigned short h[8] = {
            (unsigned short)(v.x & 0xFFFF), (unsigned short)(v.x >> 16),
            (unsigned short)(v.y & 0xFFFF), (unsigned short)(v.y >> 16),
            (unsigned short)(v.z & 0xFFFF), (unsigned short)(v.z >> 16),
            (unsigned short)(v.w & 0xFFFF), (unsigned short)(v.w >> 16)};
#pragma unroll
        for (int e = 0; e < 8; ++e)
            *(unsigned short*)&lds[e * REG + base] = h[e];
    }
    __syncthreads();

    int lane = tid & 63;
    int wid = tid >> 6;
    int l15 = lane & 15, l4 = lane >> 4;

    // this wave's p-pair: pA, pA+1 (share i0k; w differs)
    int pA = p0 + wid * 2;
    float posA = ((float)pA + 0.5f) * (1.0f / 128.0f) - 0.5f;
    posA = fmaxf(posA, 0.0f);
    int i0k = (int)posA;
    bool clamp = (i0k >= KK - 1);
    float wq[2];
#pragma unroll
    for (int q = 0; q < 2; ++q) {
        float pos = ((float)(pA + q) + 0.5f) * (1.0f / 128.0f) - 0.5f;
        pos = fmaxf(pos, 0.0f);
        wq[q] = clamp ? 0.0f : (pos - (float)i0k);
    }
    const float* mb0 = Pmag + (size_t)i0k * 4096;
    const float* pb0 = Pph + (size_t)i0k * 4096;

    f4v accR[2][4], accI[2][4];
#pragma unroll
    for (int q = 0; q < 2; ++q)
#pragma unroll
        for (int ic = 0; ic < 4; ++ic) { accR[q][ic] = (f4v)0.0f; accI[q][ic] = (f4v)0.0f; }

#pragma unroll
    for (int jc = 0; jc < 2; ++jc) {
        int jb2 = (jc * 32 + l4 * 8) * 2;    // byte offset of A-frag j-slice
        s8v xR0 = *(const s8v*)&lds[(wid * 2 + 0) * REG + l15 * 144 + jb2];
        s8v xI0 = *(const s8v*)&lds[(wid * 2 + 0) * REG + 2304 + l15 * 144 + jb2];
        s8v xR1 = *(const s8v*)&lds[(wid * 2 + 1) * REG + l15 * 144 + jb2];
        s8v xI1 = *(const s8v*)&lds[(wid * 2 + 1) * REG + 2304 + l15 * 144 + jb2];
#pragma unroll
        for (int ic = 0; ic < 4; ++ic) {
            int tb = (ic * 2 + jc) * 512 + lane * 8;   // coalesced: wave reads 2KB burst
            float4 m0a = *(const float4*)(mb0 + tb);
            float4 m0b = *(const float4*)(mb0 + tb + 4);
            float4 m1a = *(const float4*)(mb0 + 4096 + tb);
            float4 m1b = *(const float4*)(mb0 + 4096 + tb + 4);
            float4 q0a = *(const float4*)(pb0 + tb);
            float4 q0b = *(const float4*)(pb0 + tb + 4);
            float4 q1a = *(const float4*)(pb0 + 4096 + tb);
            float4 q1b = *(const float4*)(pb0 + 4096 + tb + 4);
            float m0v[8] = {m0a.x, m0a.y, m0a.z, m0a.w, m0b.x, m0b.y, m0b.z, m0b.w};
            float m1v[8] = {m1a.x, m1a.y, m1a.z, m1a.w, m1b.x, m1b.y, m1b.z, m1b.w};
            float q0v[8] = {q0a.x, q0a.y, q0a.z, q0a.w, q0b.x, q0b.y, q0b.z, q0b.w};
            float q1v[8] = {q1a.x, q1a.y, q1a.z, q1a.w, q1b.x, q1b.y, q1b.z, q1b.w};
#pragma unroll
            for (int q = 0; q < 2; ++q) {
                float w = wq[q];
                float kr[8], ki[8];
#pragma unroll
                for (int e = 0; e < 8; ++e) {
                    float mm = m0v[e] + (m1v[e] - m0v[e]) * w;
                    float ph = q0v[e] + (q1v[e] - q0v[e]) * w;
                    float sn, cs;
                    nsincos(ph, &sn, &cs);
                    kr[e] = mm * cs;
                    ki[e] = mm * sn;
                }
                union { unsigned u[4]; s8v v; } kR, kIp, kIn;
#pragma unroll
                for (int t = 0; t < 4; ++t) {
                    kR.u[t] = pkbf(kr[2 * t], kr[2 * t + 1]);
                    kIp.u[t] = pkbf(ki[2 * t], ki[2 * t + 1]);
                    kIn.u[t] = kIp.u[t] ^ 0x80008000u;
                }
                s8v xR = q ? xR1 : xR0;
                s8v xI = q ? xI1 : xI0;
                accR[q][ic] = __builtin_amdgcn_mfma_f32_16x16x32_bf16(xR, kR.v, accR[q][ic], 0, 0, 0);
                accR[q][ic] = __builtin_amdgcn_mfma_f32_16x16x32_bf16(xI, kIn.v, accR[q][ic], 0, 0, 0);
                accI[q][ic] = __builtin_amdgcn_mfma_f32_16x16x32_bf16(xR, kIp.v, accI[q][ic], 0, 0, 0);
                accI[q][ic] = __builtin_amdgcn_mfma_f32_16x16x32_bf16(xI, kR.v, accI[q][ic], 0, 0, 0);
            }
        }
    }

    // overlay: out[b][i] bf16x2 into this wave's (now dead) x regions
#pragma unroll
    for (int q = 0; q < 2; ++q) {
        int pp = wid * 2 + q;
#pragma unroll
        for (int ic = 0; ic < 4; ++ic) {
#pragma unroll
            for (int e = 0; e < 4; ++e) {
                int row = (l4 * 4 + e) * 64 + ic * 16 + l15;   // b*64 + i
                unsigned val = ((unsigned)f2bf(accI[q][ic][e]) << 16) | f2bf(accR[q][ic][e]);
                *(unsigned*)&lds[pp * REG + row * 4] = val;
            }
        }
    }
    __syncthreads();

#pragma unroll
    for (int k = 0; k < 32; ++k) {
        int row = k * 32 + (tid >> 3);
        unsigned v = *(const unsigned*)&lds[(tid & 7) * REG + row * 4];
        outd[(size_t)row * 8192 + p0 + (tid & 7)] = v;
    }
}

// ---------------- kernel 6: radix-4 inverse DIF FFT + bitrev permute + activation ----------------
__global__ __launch_bounds__(512) void k_ifft(const __hip_bfloat162* __restrict__ outfft,
                                              const float* __restrict__ alpha_,
                                              float* __restrict__ out) {
    __shared__ float sRe[L];
    __shared__ float sIm[L];
    int row = blockIdx.x;          // b*64 + i
    int tid = threadIdx.x;
    float alpha = alpha_[0];
    size_t base = (size_t)row * L;

    for (int rpt = 0; rpt < L / 512; ++rpt) {
        int idx = rpt * 512 + tid;
        __hip_bfloat162 v = outfft[base + idx];
        sRe[idx] = __bfloat162float(v.x);
        sIm[idx] = __bfloat162float(v.y);
    }

    for (int sp = 0; sp < 6; ++sp) {
        int lg2v = 11 - 2 * sp;
        int len2 = 1 << lg2v;
        float hs = 0.f, hc = 1.f;
        if (sp >= 1) {
            int j1 = tid & (len2 - 1);
            nsincos(PI_F * (float)j1 / (float)(2 * len2), &hs, &hc);
        }
        __syncthreads();
#pragma unroll
        for (int rpt = 0; rpt < 4; ++rpt) {
            int t = rpt * 512 + tid;
            int j1 = t & (len2 - 1);
            int idx = ((t >> lg2v) << (lg2v + 2)) | j1;
            float c1 = hc, s1 = hs;
            if (sp == 0) nsincos(PI_F * (float)j1 / (float)(2 * len2), &s1, &c1);
            float c2 = c1 * c1 - s1 * s1, s2 = 2.f * c1 * s1;
            float u0r = sRe[idx],            u0i = sIm[idx];
            float u1r = sRe[idx + len2],     u1i = sIm[idx + len2];
            float v0r = sRe[idx + 2*len2],   v0i = sIm[idx + 2*len2];
            float v1r = sRe[idx + 3*len2],   v1i = sIm[idx + 3*len2];
            float A0r = u0r + v0r, A0i = u0i + v0i;
            float t0r = u0r - v0r, t0i = u0i - v0i;
            float B0r = t0r * c1 - t0i * s1, B0i = t0r * s1 + t0i * c1;
            float A1r = u1r + v1r, A1i = u1i + v1i;
            float t1r = u1r - v1r, t1i = u1i - v1i;
            float w1r = t1r * c1 - t1i * s1, w1i = t1r * s1 + t1i * c1;
            float B1r = -w1i, B1i = w1r;    // * (+i)
            sRe[idx] = A0r + A1r;            sIm[idx] = A0i + A1i;
            float d0r = A0r - A1r, d0i = A0i - A1i;
            sRe[idx + len2] = d0r * c2 - d0i * s2;
            sIm[idx + len2] = d0r * s2 + d0i * c2;
            sRe[idx + 2*len2] = B0r + B1r;   sIm[idx + 2*len2] = B0i + B1i;
            float d1r = B0r - B1r, d1i = B0i - B1i;
            sRe[idx + 3*len2] = d1r * c2 - d1i * s2;
            sIm[idx + 3*len2] = d1r * s2 + d1i * c2;
        }
    }
    __syncthreads();
#pragma unroll
    for (int rpt = 0; rpt < 8; ++rpt) {
        int idx = (rpt * 512 + tid) * 2;
        float ar = sRe[idx], ai = sIm[idx];
        float br = sRe[idx + 1], bi = sIm[idx + 1];
        sRe[idx] = ar + br;     sIm[idx] = ai + bi;
        sRe[idx + 1] = ar - br; sIm[idx + 1] = ai - bi;
    }
    __syncthreads();

    float vr[16], vi[16];
#pragma unroll
    for (int r = 0; r < 16; ++r) {
        int idx = r * 512 + tid;
        vr[r] = sRe[idx]; vi[r] = sIm[idx];
    }
    __syncthreads();
#pragma unroll
    for (int r = 0; r < 16; ++r) {
        int idx = r * 512 + tid;
        int n = (int)(__brev((unsigned)idx) >> 19);
        int a = swz(n);
        sRe[a] = vr[r]; sIm[a] = vi[r];
    }
    __syncthreads();

    const float invN = 1.0f / (float)L;
#pragma unroll
    for (int rpt = 0; rpt < L / 512; ++rpt) {
        int n = rpt * 512 + tid;
        float act = sinf(alpha * (float)n);
        out[base + n] = sRe[swz(n)] * act * invN;
    }
}

// ---------------- launch ----------------
extern "C" void kernel_launch(void* const* d_in, const int* in_sizes, int n_in,
                              void* d_out, int out_size, void* d_ws, size_t ws_size,
                              hipStream_t stream) {
    const float* xr = (const float*)d_in[0];
    const float* xi = (const float*)d_in[1];
    const float* kr = (const float*)d_in[2];
    const float* ki = (const float*)d_in[3];
    const float* alpha = (const float*)d_in[4];
    float* out = (float*)d_out;

    char* ws = (char*)d_ws;
    size_t OFFT_BYTES = (size_t)B * COUT * L * 4;
    size_t TBL_BYTES = (size_t)65 * 4096 * 4;
    unsigned* outfft_d = (unsigned*)ws;
    float* Pmag = (float*)(ws + OFFT_BYTES);
    float* Pph  = (float*)(ws + OFFT_BYTES + TBL_BYTES);
    float* pmin = (float*)(ws + OFFT_BYTES + 2 * TBL_BYTES);
    float* pmax = pmin + 1024;
    float* mmin = pmax + 1024;
    float* mmax = mmin + 16;

    unsigned* xplanar = (unsigned*)d_out;

    hipLaunchKernelGGL(k_reduce1, dim3(1024), dim3(256), 0, stream, xr, xi, pmin, pmax);
    hipLaunchKernelGGL(k_reduce2, dim3(16), dim3(64), 0, stream, pmin, pmax, mmin, mmax);
    hipLaunchKernelGGL(k_kstats, dim3(4096), dim3(64), 0, stream, kr, ki, Pmag, Pph);
    hipLaunchKernelGGL(k_fwd, dim3(1024), dim3(512), 0, stream, xr, xi, mmin, mmax, xplanar);
    hipLaunchKernelGGL(k_gemm, dim3(1024), dim3(256), 0, stream,
                       (const unsigned short*)xplanar, Pmag, Pph, outfft_d);
    hipLaunchKernelGGL(k_ifft, dim3(1024), dim3(512), 0, stream,
                       (const __hip_bfloat162*)outfft_d, alpha, out);
}

// Round 13
// 135.944 us; speedup vs baseline: 1.6871x; 1.1745x over previous
//
#include <hip/hip_runtime.h>
#include <hip/hip_fp16.h>
#include <hip/hip_bf16.h>
#include <math.h>

#define L 8192
#define LOG2L 13
#define B 16
#define CIN 64
#define COUT 64
#define KK 64

#define PI_F 3.14159265358979323846f

typedef float f4v __attribute__((ext_vector_type(4)));
typedef short s8v __attribute__((ext_vector_type(8)));

// scatter swizzle for the bit-reversal permute (unchanged, ~2-way on scatter)
__device__ __forceinline__ int swz(int n) { return n ^ ((n >> 8) & 31); }
// butterfly-storage swizzle: XOR bits 1-4 with f(bits>=5); bijective, b64-preserving.
// Makes all three radix-16 passes <=2-way bank-conflicted (free).
__device__ __forceinline__ int PHI(int n) { return n ^ ((((n >> 5) ^ (n >> 9)) & 15) << 1); }

// native sincos (revolutions + fract range reduction)
__device__ __forceinline__ void nsincos(float ang, float* sn, float* cs) {
    float r = ang * 0.15915494309189535f;
    r = r - floorf(r);
    *sn = __builtin_amdgcn_sinf(r);
    *cs = __builtin_amdgcn_cosf(r);
}

// f32 -> bf16 bits, round-to-nearest-even
__device__ __forceinline__ unsigned short f2bf(float f) {
    unsigned u = __builtin_bit_cast(unsigned, f);
    u += 0x7FFFu + ((u >> 16) & 1u);
    return (unsigned short)(u >> 16);
}
// pack two f32 -> bf16x2 dword (round-half-up)
__device__ __forceinline__ unsigned pkbf(float a, float b) {
    unsigned ua = __builtin_bit_cast(unsigned, a) + 0x8000u;
    unsigned ub = __builtin_bit_cast(unsigned, b) + 0x8000u;
    return (ub & 0xFFFF0000u) | (ua >> 16);
}

// fused radix-4 butterfly (two radix-2 stages), verified in rounds 10-12.
// (u0,u1,v0,v1) at relative offsets (0, len2, 2len2, 3len2); W1 = e^{∓iθ4}, W2 = W1².
template<int INV>
__device__ __forceinline__ void bfly4(float& u0r, float& u0i, float& u1r, float& u1i,
                                      float& v0r, float& v0i, float& v1r, float& v1i,
                                      float w1r, float w1i, float w2r, float w2i) {
    float A0r = u0r + v0r, A0i = u0i + v0i;
    float t0r = u0r - v0r, t0i = u0i - v0i;
    float B0r = t0r * w1r - t0i * w1i, B0i = t0r * w1i + t0i * w1r;
    float A1r = u1r + v1r, A1i = u1i + v1i;
    float t1r = u1r - v1r, t1i = u1i - v1i;
    float wr = t1r * w1r - t1i * w1i, wi = t1r * w1i + t1i * w1r;
    float B1r = INV ? -wi : wi;     // * (±i)
    float B1i = INV ? wr : -wr;
    u0r = A0r + A1r; u0i = A0i + A1i;
    float d0r = A0r - A1r, d0i = A0i - A1i;
    u1r = d0r * w2r - d0i * w2i; u1i = d0r * w2i + d0i * w2r;
    v0r = B0r + B1r; v0i = B0i + B1i;
    float d1r = B0r - B1r, d1i = B0i - B1i;
    v1r = d1r * w2r - d1i * w2i; v1i = d1r * w2i + d1i * w2r;
}

// radix-16 (4 fused radix-2 stages) on 16 register points at stride len2.
// (wc,ws) = e^{∓iθ}, θ = π j1 / (8 len2). Sub-A twiddles w·e^{∓iqπ/8}; sub-B w⁴, w⁸.
template<int INV>
__device__ __forceinline__ void radix16(float* xr, float* xi, float wc, float ws) {
    const float C8 = 0.9238795325112867f, S8 = 0.3826834323650898f, C4 = 0.7071067811865476f;
    float e1r = C8, e1i = INV ? S8 : -S8;
    float e2r = C4, e2i = INV ? C4 : -C4;
    float e3r = S8, e3i = INV ? C8 : -C8;
    float a1r[4], a1i[4], a2r[4], a2i[4];
    a1r[0] = wc;                    a1i[0] = ws;
    a1r[1] = wc * e1r - ws * e1i;   a1i[1] = wc * e1i + ws * e1r;
    a1r[2] = wc * e2r - ws * e2i;   a1i[2] = wc * e2i + ws * e2r;
    a1r[3] = wc * e3r - ws * e3i;   a1i[3] = wc * e3i + ws * e3r;
#pragma unroll
    for (int q = 0; q < 4; ++q) {
        a2r[q] = a1r[q] * a1r[q] - a1i[q] * a1i[q];
        a2i[q] = 2.f * a1r[q] * a1i[q];
    }
    float b1r = a2r[0] * a2r[0] - a2i[0] * a2i[0], b1i = 2.f * a2r[0] * a2i[0];
    float b2r = b1r * b1r - b1i * b1i, b2i = 2.f * b1r * b1i;
#pragma unroll
    for (int q = 0; q < 4; ++q)
        bfly4<INV>(xr[q], xi[q], xr[q + 4], xi[q + 4], xr[q + 8], xi[q + 8],
                   xr[q + 12], xi[q + 12], a1r[q], a1i[q], a2r[q], a2i[q]);
#pragma unroll
    for (int c = 0; c < 4; ++c)
        bfly4<INV>(xr[4 * c], xi[4 * c], xr[4 * c + 1], xi[4 * c + 1],
                   xr[4 * c + 2], xi[4 * c + 2], xr[4 * c + 3], xi[4 * c + 3],
                   b1r, b1i, b2r, b2i);
}

// ---------------- kernel 1: partial per-batch min/max of |x| ----------------
__global__ __launch_bounds__(256) void k_reduce1(const float* __restrict__ xr,
                                                 const float* __restrict__ xi,
                                                 float* __restrict__ pmin,
                                                 float* __restrict__ pmax) {
    int bid = blockIdx.x;
    int batch = bid >> 6, slice = bid & 63;
    size_t base = (size_t)batch * CIN * L + (size_t)slice * L;
    int tid = threadIdx.x;
    float mn = 3.4e38f, mx = 0.0f;
    for (int r = 0; r < 32; ++r) {
        int idx = r * 256 + tid;
        float a = xr[base + idx], b = xi[base + idx];
        float m = sqrtf(a * a + b * b);
        mn = fminf(mn, m);
        mx = fmaxf(mx, m);
    }
    __shared__ float smn[4], smx[4];
    for (int off = 32; off >= 1; off >>= 1) {
        mn = fminf(mn, __shfl_down(mn, off));
        mx = fmaxf(mx, __shfl_down(mx, off));
    }
    int wave = tid >> 6;
    if ((tid & 63) == 0) { smn[wave] = mn; smx[wave] = mx; }
    __syncthreads();
    if (tid == 0) {
        for (int w = 1; w < 4; ++w) { mn = fminf(mn, smn[w]); mx = fmaxf(mx, smx[w]); }
        pmin[bid] = mn;
        pmax[bid] = mx;
    }
}

// ---------------- kernel 2: final min/max ----------------
__global__ __launch_bounds__(64) void k_reduce2(const float* __restrict__ pmin,
                                                const float* __restrict__ pmax,
                                                float* __restrict__ mmin,
                                                float* __restrict__ mmax) {
    int b = blockIdx.x, t = threadIdx.x;
    float mn = pmin[b * 64 + t], mx = pmax[b * 64 + t];
    for (int off = 32; off >= 1; off >>= 1) {
        mn = fminf(mn, __shfl_down(mn, off));
        mx = fmaxf(mx, __shfl_down(mx, off));
    }
    if (t == 0) { mmin[b] = mn; mmax[b] = mx; }
}

// ---------------- kernel 3: kernel FFT stats, B-FRAGMENT-PACKED tables ----------------
__global__ __launch_bounds__(64) void k_kstats(const float* __restrict__ kr,
                                               const float* __restrict__ ki,
                                               float* __restrict__ Pmag,
                                               float* __restrict__ Pph) {
    int row = blockIdx.x;   // io*64 + jn
    int k = threadIdx.x;
    __shared__ float sr[64], si[64];
    sr[k] = kr[row * 64 + k];
    si[k] = ki[row * 64 + k];
    __syncthreads();
    float ar = 0.f, ai = 0.f;
    for (int n = 0; n < 64; ++n) {
        int m = (n * k) & 63;
        float ang = -2.0f * PI_F * (float)m * (1.0f / 64.0f);
        float s, c;
        __sincosf(ang, &s, &c);
        ar += sr[n] * c - si[n] * s;
        ai += sr[n] * s + si[n] * c;
    }
    float mag = sqrtf(ar * ar + ai * ai);
    float ph = atan2f(ai, ar);
    int io = row >> 6, jn = row & 63;
    int ic = io >> 4, l15 = io & 15;
    int jc = jn >> 5, hi = (jn >> 3) & 3, e = jn & 7;
    int lane = hi * 16 + l15;
    size_t off = (size_t)k * 4096 + (ic * 2 + jc) * 512 + lane * 8 + e;
    Pmag[off] = mag;
    Pph[off] = ph;
    if (k == 63) {
        Pmag[off + 4096] = mag;
        Pph[off + 4096] = ph;
    }
}

// ---------------- kernel 4: coupling + stage0-in-regs + 3 radix-16 passes + permute ----------------
// x_fft written PLANAR bf16 into d_out (R plane then I plane).
__global__ __launch_bounds__(512) void k_fwd(const float* __restrict__ xr,
                                             const float* __restrict__ xi,
                                             const float* __restrict__ mmin_,
                                             const float* __restrict__ mmax_,
                                             unsigned* __restrict__ xRd) {
    __shared__ float sRe[L];
    __shared__ float sIm[L];
    int row = blockIdx.x;          // b*64 + j
    int b = row >> 6;
    int tid = threadIdx.x;
    float mmin = mmin_[b], mmax = mmax_[b];
    float span = mmax - mmin;
    float invden = 1.0f / (span + 1e-10f);
    size_t base = (size_t)row * L;

    float vr[16], vi[16];
    // coupling into registers (16 points: idx = r*512 + tid)
#pragma unroll
    for (int r = 0; r < 16; ++r) {
        int idx = r * 512 + tid;
        float a = xr[base + idx], c = xi[base + idx];
        float m = sqrtf(a * a + c * c);
        float xn = (m - mmin) * invden;
#pragma unroll
        for (int it = 0; it < 5; ++it) xn = 3.8f * xn * (1.0f - xn);
        float mc = xn * span + mmin;
        float scale = (m > 0.0f) ? (mc / m) : 0.0f;
        vr[r] = a * scale;
        vi[r] = c * scale;
    }
    // stage 0 (len 4096) in registers: pairs (r, r+8), W = e^{-i pi (r*512+tid)/4096}
#pragma unroll
    for (int r = 0; r < 8; ++r) {
        float sn, cs;
        nsincos(-PI_F * (float)(r * 512 + tid) * (1.0f / 4096.0f), &sn, &cs);
        float ar = vr[r], ai = vi[r], br = vr[r + 8], bi = vi[r + 8];
        vr[r] = ar + br; vi[r] = ai + bi;
        float dr = ar - br, di = ai - bi;
        vr[r + 8] = dr * cs - di * sn;
        vi[r + 8] = dr * sn + di * cs;
    }
#pragma unroll
    for (int r = 0; r < 16; ++r) {
        int a = PHI(r * 512 + tid);
        sRe[a] = vr[r]; sIm[a] = vi[r];
    }
    __syncthreads();

    // pass A: stages 1-4, len2=256
    {
        int j1 = tid & 255, bA = (tid >> 8) << 12;
#pragma unroll
        for (int m = 0; m < 16; ++m) {
            int a = PHI(bA + j1 + (m << 8));
            vr[m] = sRe[a]; vi[m] = sIm[a];
        }
        float sn, cs;
        nsincos(-PI_F * (float)j1 * (1.0f / 2048.0f), &sn, &cs);
        radix16<0>(vr, vi, cs, sn);
#pragma unroll
        for (int m = 0; m < 16; ++m) {
            int a = PHI(bA + j1 + (m << 8));
            sRe[a] = vr[m]; sIm[a] = vi[m];
        }
    }
    __syncthreads();
    // pass B: stages 5-8, len2=16
    {
        int j1 = tid & 15, bB = (tid >> 4) << 8;
#pragma unroll
        for (int m = 0; m < 16; ++m) {
            int a = PHI(bB + j1 + (m << 4));
            vr[m] = sRe[a]; vi[m] = sIm[a];
        }
        float sn, cs;
        nsincos(-PI_F * (float)j1 * (1.0f / 128.0f), &sn, &cs);
        radix16<0>(vr, vi, cs, sn);
#pragma unroll
        for (int m = 0; m < 16; ++m) {
            int a = PHI(bB + j1 + (m << 4));
            sRe[a] = vr[m]; sIm[a] = vi[m];
        }
    }
    __syncthreads();
    // pass C: stages 9-12, len2=1 (consecutive 16; float2 ops; constant twiddles)
    {
        float2* f2R = (float2*)sRe;
        float2* f2I = (float2*)sIm;
#pragma unroll
        for (int m = 0; m < 8; ++m) {
            int a = PHI(tid * 16 + 2 * m) >> 1;
            float2 vR = f2R[a], vI = f2I[a];
            vr[2 * m] = vR.x; vr[2 * m + 1] = vR.y;
            vi[2 * m] = vI.x; vi[2 * m + 1] = vI.y;
        }
        radix16<0>(vr, vi, 1.0f, 0.0f);
#pragma unroll
        for (int m = 0; m < 8; ++m) {
            int a = PHI(tid * 16 + 2 * m) >> 1;
            f2R[a] = make_float2(vr[2 * m], vr[2 * m + 1]);
            f2I[a] = make_float2(vi[2 * m], vi[2 * m + 1]);
        }
    }
    __syncthreads();

    // bitrev permute: read linear (PHI layout) -> scatter to swz layout
#pragma unroll
    for (int r = 0; r < 16; ++r) {
        int a = PHI(r * 512 + tid);
        vr[r] = sRe[a]; vi[r] = sIm[a];
    }
    __syncthreads();
#pragma unroll
    for (int r = 0; r < 16; ++r) {
        int idx = r * 512 + tid;
        int n = (int)(__brev((unsigned)idx) >> 19);
        int a = swz(n);
        sRe[a] = vr[r]; sIm[a] = vi[r];
    }
    __syncthreads();

    // planar bf16 write, natural order
    unsigned* xId = xRd + (size_t)1024 * 4096;
#pragma unroll
    for (int r = 0; r < 8; ++r) {
        int n2 = r * 1024 + tid * 2;
        int a0 = swz(n2), a1 = swz(n2 + 1);
        unsigned vR = ((unsigned)f2bf(sRe[a1]) << 16) | f2bf(sRe[a0]);
        unsigned vI = ((unsigned)f2bf(sIm[a1]) << 16) | f2bf(sIm[a0]);
        size_t o = (size_t)row * 4096 + (n2 >> 1);
        xRd[o] = vR;
        xId[o] = vI;
    }
}

// ---------------- kernel 5: MFMA complex GEMM over frequencies (unchanged) ----------------
#define PB 8
#define REG 4624
__global__ __launch_bounds__(256) void k_gemm(const unsigned short* __restrict__ xp,
                                              const float* __restrict__ Pmag,
                                              const float* __restrict__ Pph,
                                              unsigned* __restrict__ outd) {
    __shared__ uint4 ldsbuf[(PB * REG) / 16];
    char* lds = (char*)ldsbuf;
    int tid = threadIdx.x;
    int bid = blockIdx.x;
    int pwin = ((bid & 7) << 7) + (bid >> 3);
    int p0 = pwin * PB;

#pragma unroll
    for (int r = 0; r < 8; ++r) {
        int u = r * 256 + tid;
        int plane = u >> 10;
        int row = u & 1023;
        uint4 v = *(const uint4*)&xp[(size_t)plane * 8388608 + (size_t)row * 8192 + p0];
        int base = plane * 2304 + (row >> 6) * 144 + (row & 63) * 2;
        unsigned short h[8] = {
            (unsigned short)(v.x & 0xFFFF), (unsigned short)(v.x >> 16),
            (unsigned short)(v.y & 0xFFFF), (unsigned short)(v.y >> 16),
            (unsigned short)(v.z & 0xFFFF), (unsigned short)(v.z >> 16),
            (unsigned short)(v.w & 0xFFFF), (unsigned short)(v.w >> 16)};
#pragma unroll
        for (int e = 0; e < 8; ++e)
            *(unsigned short*)&lds[e * REG + base] = h[e];
    }
    __syncthreads();

    int lane = tid & 63;
    int wid = tid >> 6;
    int l15 = lane & 15, l4 = lane >> 4;

    int pA = p0 + wid * 2;
    float posA = ((float)pA + 0.5f) * (1.0f / 128.0f) - 0.5f;
    posA = fmaxf(posA, 0.0f);
    int i0k = (int)posA;
    bool clamp = (i0k >= KK - 1);
    float wq[2];
#pragma unroll
    for (int q = 0; q < 2; ++q) {
        float pos = ((float)(pA + q) + 0.5f) * (1.0f / 128.0f) - 0.5f;
        pos = fmaxf(pos, 0.0f);
        wq[q] = clamp ? 0.0f : (pos - (float)i0k);
    }
    const float* mb0 = Pmag + (size_t)i0k * 4096;
    const float* pb0 = Pph + (size_t)i0k * 4096;

    f4v accR[2][4], accI[2][4];
#pragma unroll
    for (int q = 0; q < 2; ++q)
#pragma unroll
        for (int ic = 0; ic < 4; ++ic) { accR[q][ic] = (f4v)0.0f; accI[q][ic] = (f4v)0.0f; }

#pragma unroll
    for (int jc = 0; jc < 2; ++jc) {
        int jb2 = (jc * 32 + l4 * 8) * 2;
        s8v xR0 = *(const s8v*)&lds[(wid * 2 + 0) * REG + l15 * 144 + jb2];
        s8v xI0 = *(const s8v*)&lds[(wid * 2 + 0) * REG + 2304 + l15 * 144 + jb2];
        s8v xR1 = *(const s8v*)&lds[(wid * 2 + 1) * REG + l15 * 144 + jb2];
        s8v xI1 = *(const s8v*)&lds[(wid * 2 + 1) * REG + 2304 + l15 * 144 + jb2];
#pragma unroll
        for (int ic = 0; ic < 4; ++ic) {
            int tb = (ic * 2 + jc) * 512 + lane * 8;
            float4 m0a = *(const float4*)(mb0 + tb);
            float4 m0b = *(const float4*)(mb0 + tb + 4);
            float4 m1a = *(const float4*)(mb0 + 4096 + tb);
            float4 m1b = *(const float4*)(mb0 + 4096 + tb + 4);
            float4 q0a = *(const float4*)(pb0 + tb);
            float4 q0b = *(const float4*)(pb0 + tb + 4);
            float4 q1a = *(const float4*)(pb0 + 4096 + tb);
            float4 q1b = *(const float4*)(pb0 + 4096 + tb + 4);
            float m0v[8] = {m0a.x, m0a.y, m0a.z, m0a.w, m0b.x, m0b.y, m0b.z, m0b.w};
            float m1v[8] = {m1a.x, m1a.y, m1a.z, m1a.w, m1b.x, m1b.y, m1b.z, m1b.w};
            float q0v[8] = {q0a.x, q0a.y, q0a.z, q0a.w, q0b.x, q0b.y, q0b.z, q0b.w};
            float q1v[8] = {q1a.x, q1a.y, q1a.z, q1a.w, q1b.x, q1b.y, q1b.z, q1b.w};
#pragma unroll
            for (int q = 0; q < 2; ++q) {
                float w = wq[q];
                float kr[8], ki[8];
#pragma unroll
                for (int e = 0; e < 8; ++e) {
                    float mm = m0v[e] + (m1v[e] - m0v[e]) * w;
                    float ph = q0v[e] + (q1v[e] - q0v[e]) * w;
                    float sn, cs;
                    nsincos(ph, &sn, &cs);
                    kr[e] = mm * cs;
                    ki[e] = mm * sn;
                }
                union { unsigned u[4]; s8v v; } kR, kIp, kIn;
#pragma unroll
                for (int t = 0; t < 4; ++t) {
                    kR.u[t] = pkbf(kr[2 * t], kr[2 * t + 1]);
                    kIp.u[t] = pkbf(ki[2 * t], ki[2 * t + 1]);
                    kIn.u[t] = kIp.u[t] ^ 0x80008000u;
                }
                s8v xR = q ? xR1 : xR0;
                s8v xI = q ? xI1 : xI0;
                accR[q][ic] = __builtin_amdgcn_mfma_f32_16x16x32_bf16(xR, kR.v, accR[q][ic], 0, 0, 0);
                accR[q][ic] = __builtin_amdgcn_mfma_f32_16x16x32_bf16(xI, kIn.v, accR[q][ic], 0, 0, 0);
                accI[q][ic] = __builtin_amdgcn_mfma_f32_16x16x32_bf16(xR, kIp.v, accI[q][ic], 0, 0, 0);
                accI[q][ic] = __builtin_amdgcn_mfma_f32_16x16x32_bf16(xI, kR.v, accI[q][ic], 0, 0, 0);
            }
        }
    }

#pragma unroll
    for (int q = 0; q < 2; ++q) {
        int pp = wid * 2 + q;
#pragma unroll
        for (int ic = 0; ic < 4; ++ic) {
#pragma unroll
            for (int e = 0; e < 4; ++e) {
                int row = (l4 * 4 + e) * 64 + ic * 16 + l15;
                unsigned val = ((unsigned)f2bf(accI[q][ic][e]) << 16) | f2bf(accR[q][ic][e]);
                *(unsigned*)&lds[pp * REG + row * 4] = val;
            }
        }
    }
    __syncthreads();

#pragma unroll
    for (int k = 0; k < 32; ++k) {
        int row = k * 32 + (tid >> 3);
        unsigned v = *(const unsigned*)&lds[(tid & 7) * REG + row * 4];
        outd[(size_t)row * 8192 + p0 + (tid & 7)] = v;
    }
}

// ---------------- kernel 6: inverse FFT (stage0-in-regs + 3 radix-16) + activation ----------------
__global__ __launch_bounds__(512) void k_ifft(const __hip_bfloat162* __restrict__ outfft,
                                              const float* __restrict__ alpha_,
                                              float* __restrict__ out) {
    __shared__ float sRe[L];
    __shared__ float sIm[L];
    int row = blockIdx.x;          // b*64 + i
    int tid = threadIdx.x;
    float alpha = alpha_[0];
    size_t base = (size_t)row * L;

    float vr[16], vi[16];
#pragma unroll
    for (int r = 0; r < 16; ++r) {
        __hip_bfloat162 v = outfft[base + r * 512 + tid];
        vr[r] = __bfloat162float(v.x);
        vi[r] = __bfloat162float(v.y);
    }
    // stage 0, positive twiddles
#pragma unroll
    for (int r = 0; r < 8; ++r) {
        float sn, cs;
        nsincos(PI_F * (float)(r * 512 + tid) * (1.0f / 4096.0f), &sn, &cs);
        float ar = vr[r], ai = vi[r], br = vr[r + 8], bi = vi[r + 8];
        vr[r] = ar + br; vi[r] = ai + bi;
        float dr = ar - br, di = ai - bi;
        vr[r + 8] = dr * cs - di * sn;
        vi[r + 8] = dr * sn + di * cs;
    }
#pragma unroll
    for (int r = 0; r < 16; ++r) {
        int a = PHI(r * 512 + tid);
        sRe[a] = vr[r]; sIm[a] = vi[r];
    }
    __syncthreads();

    // pass A
    {
        int j1 = tid & 255, bA = (tid >> 8) << 12;
#pragma unroll
        for (int m = 0; m < 16; ++m) {
            int a = PHI(bA + j1 + (m << 8));
            vr[m] = sRe[a]; vi[m] = sIm[a];
        }
        float sn, cs;
        nsincos(PI_F * (float)j1 * (1.0f / 2048.0f), &sn, &cs);
        radix16<1>(vr, vi, cs, sn);
#pragma unroll
        for (int m = 0; m < 16; ++m) {
            int a = PHI(bA + j1 + (m << 8));
            sRe[a] = vr[m]; sIm[a] = vi[m];
        }
    }
    __syncthreads();
    // pass B
    {
        int j1 = tid & 15, bB = (tid >> 4) << 8;
#pragma unroll
        for (int m = 0; m < 16; ++m) {
            int a = PHI(bB + j1 + (m << 4));
            vr[m] = sRe[a]; vi[m] = sIm[a];
        }
        float sn, cs;
        nsincos(PI_F * (float)j1 * (1.0f / 128.0f), &sn, &cs);
        radix16<1>(vr, vi, cs, sn);
#pragma unroll
        for (int m = 0; m < 16; ++m) {
            int a = PHI(bB + j1 + (m << 4));
            sRe[a] = vr[m]; sIm[a] = vi[m];
        }
    }
    __syncthreads();
    // pass C
    {
        float2* f2R = (float2*)sRe;
        float2* f2I = (float2*)sIm;
#pragma unroll
        for (int m = 0; m < 8; ++m) {
            int a = PHI(tid * 16 + 2 * m) >> 1;
            float2 vR = f2R[a], vI = f2I[a];
            vr[2 * m] = vR.x; vr[2 * m + 1] = vR.y;
            vi[2 * m] = vI.x; vi[2 * m + 1] = vI.y;
        }
        radix16<1>(vr, vi, 1.0f, 0.0f);
#pragma unroll
        for (int m = 0; m < 8; ++m) {
            int a = PHI(tid * 16 + 2 * m) >> 1;
            f2R[a] = make_float2(vr[2 * m], vr[2 * m + 1]);
            f2I[a] = make_float2(vi[2 * m], vi[2 * m + 1]);
        }
    }
    __syncthreads();

    // bitrev permute to natural order
#pragma unroll
    for (int r = 0; r < 16; ++r) {
        int a = PHI(r * 512 + tid);
        vr[r] = sRe[a]; vi[r] = sIm[a];
    }
    __syncthreads();
#pragma unroll
    for (int r = 0; r < 16; ++r) {
        int idx = r * 512 + tid;
        int n = (int)(__brev((unsigned)idx) >> 19);
        int a = swz(n);
        sRe[a] = vr[r]; sIm[a] = vi[r];
    }
    __syncthreads();

    const float invN = 1.0f / (float)L;
#pragma unroll
    for (int rpt = 0; rpt < L / 512; ++rpt) {
        int n = rpt * 512 + tid;
        float act = sinf(alpha * (float)n);
        out[base + n] = sRe[swz(n)] * act * invN;
    }
}

// ---------------- launch ----------------
extern "C" void kernel_launch(void* const* d_in, const int* in_sizes, int n_in,
                              void* d_out, int out_size, void* d_ws, size_t ws_size,
                              hipStream_t stream) {
    const float* xr = (const float*)d_in[0];
    const float* xi = (const float*)d_in[1];
    const float* kr = (const float*)d_in[2];
    const float* ki = (const float*)d_in[3];
    const float* alpha = (const float*)d_in[4];
    float* out = (float*)d_out;

    char* ws = (char*)d_ws;
    size_t OFFT_BYTES = (size_t)B * COUT * L * 4;
    size_t TBL_BYTES = (size_t)65 * 4096 * 4;
    unsigned* outfft_d = (unsigned*)ws;
    float* Pmag = (float*)(ws + OFFT_BYTES);
    float* Pph  = (float*)(ws + OFFT_BYTES + TBL_BYTES);
    float* pmin = (float*)(ws + OFFT_BYTES + 2 * TBL_BYTES);
    float* pmax = pmin + 1024;
    float* mmin = pmax + 1024;
    float* mmax = mmin + 16;

    unsigned* xplanar = (unsigned*)d_out;

    hipLaunchKernelGGL(k_reduce1, dim3(1024), dim3(256), 0, stream, xr, xi, pmin, pmax);
    hipLaunchKernelGGL(k_reduce2, dim3(16), dim3(64), 0, stream, pmin, pmax, mmin, mmax);
    hipLaunchKernelGGL(k_kstats, dim3(4096), dim3(64), 0, stream, kr, ki, Pmag, Pph);
    hipLaunchKernelGGL(k_fwd, dim3(1024), dim3(512), 0, stream, xr, xi, mmin, mmax, xplanar);
    hipLaunchKernelGGL(k_gemm, dim3(1024), dim3(256), 0, stream,
                       (const unsigned short*)xplanar, Pmag, Pph, outfft_d);
    hipLaunchKernelGGL(k_ifft, dim3(1024), dim3(512), 0, stream,
                       (const __hip_bfloat162*)outfft_d, alpha, out);
}